// Round 1
// baseline (777.305 us; speedup 1.0000x reference)
//
#include <hip/hip_runtime.h>
#include <hip/hip_bf16.h>
#include <cmath>

// Problem constants
#define NN 768
#define CS 384
#define CZ 128
#define CH 16
#define HH 12
#define PQ 4
#define PV 8
#define HC (HH*CH)          // 192
#define CATC 2112           // H*(CZ+CH+PV*4)

// ---------------------------------------------------------------------------
// K1: projections q,k,v,q_pts,kv_pts (with frame application)
// grid 768 blocks x 256 threads
__global__ void k_proj(const float* __restrict__ s, const float* __restrict__ rot,
                       const float* __restrict__ trans,
                       const float* __restrict__ Wq, const float* __restrict__ bq,
                       const float* __restrict__ Wkv, const float* __restrict__ bkv,
                       const float* __restrict__ Wqp, const float* __restrict__ bqp,
                       const float* __restrict__ Wkvp, const float* __restrict__ bkvp,
                       float* __restrict__ q, float* __restrict__ kk, float* __restrict__ vv,
                       float* __restrict__ qpts, float* __restrict__ kvpts) {
  __shared__ float srow[CS];
  __shared__ float rawq[144];
  __shared__ float rawkv[432];
  __shared__ float R[9];
  __shared__ float T[3];
  int n = blockIdx.x, t = threadIdx.x;
  for (int u = t; u < CS; u += 256) srow[u] = s[(size_t)n*CS + u];
  if (t < 9) R[t] = rot[(size_t)n*9 + t];
  if (t < 3) T[t] = trans[(size_t)n*3 + t];
  __syncthreads();

  for (int col = t; col < 192; col += 256) {
    float acc = bq[col];
    for (int c = 0; c < CS; c++) acc += srow[c] * Wq[(size_t)c*192 + col];
    q[(size_t)n*192 + col] = acc;
  }
  for (int col = t; col < 384; col += 256) {
    float acc = bkv[col];
    for (int c = 0; c < CS; c++) acc += srow[c] * Wkv[(size_t)c*384 + col];
    int h = col >> 5, u2 = col & 31;
    if (u2 < 16) kk[(size_t)n*192 + h*16 + u2] = acc;
    else         vv[(size_t)n*192 + h*16 + (u2-16)] = acc;
  }
  for (int col = t; col < 144; col += 256) {
    float acc = bqp[col];
    for (int c = 0; c < CS; c++) acc += srow[c] * Wqp[(size_t)c*144 + col];
    rawq[col] = acc;
  }
  for (int col = t; col < 432; col += 256) {
    float acc = bkvp[col];
    for (int c = 0; c < CS; c++) acc += srow[c] * Wkvp[(size_t)c*432 + col];
    rawkv[col] = acc;
  }
  __syncthreads();

  // apply frame: out[x] = sum_y R[x][y]*p[y] + T[x]; pts[m][y] = raw[y*M + m]
  for (int u = t; u < 48*3; u += 256) {
    int m = u / 3, x = u % 3;
    float p0 = rawq[0*48 + m], p1 = rawq[1*48 + m], p2 = rawq[2*48 + m];
    qpts[((size_t)n*48 + m)*3 + x] = R[x*3+0]*p0 + R[x*3+1]*p1 + R[x*3+2]*p2 + T[x];
  }
  for (int u = t; u < 144*3; u += 256) {
    int m = u / 3, x = u % 3;
    float p0 = rawkv[0*144 + m], p1 = rawkv[1*144 + m], p2 = rawkv[2*144 + m];
    kvpts[((size_t)n*144 + m)*3 + x] = R[x*3+0]*p0 + R[x*3+1]*p1 + R[x*3+2]*p2 + T[x];
  }
}

// ---------------------------------------------------------------------------
// K2: logits a[h,i,j] = qk*sqrt(1/48) + sqrt(1/3)*(z[i,j]@Wb[:,h]+bb[h])
//                      - 0.5*hw[h]*sum_p |qp-kp|^2
// grid (12 j-tiles, 768 i) x 256 threads; z tile staged in LDS (pad 129)
__global__ void k_logits(const float* __restrict__ q, const float* __restrict__ kk,
                         const float* __restrict__ qpts, const float* __restrict__ kvpts,
                         const float* __restrict__ z, const float* __restrict__ Wb,
                         const float* __restrict__ bb, const float* __restrict__ head_w,
                         float* __restrict__ a) {
  __shared__ float zt[64*129];
  __shared__ float wbl[128*12];
  __shared__ float qi[192];
  __shared__ float qpi[144];
  __shared__ float hwl[12];
  __shared__ float bbl[12];
  int i = blockIdx.y, jt = blockIdx.x, t = threadIdx.x;
  int j0 = jt * 64;
  const float4* zp = (const float4*)(z + ((size_t)i*NN + j0)*CZ);
  for (int u = t; u < 2048; u += 256) {
    float4 val = zp[u];
    int jj = u >> 5, cc = (u & 31) << 2;
    float* d = zt + jj*129 + cc;
    d[0] = val.x; d[1] = val.y; d[2] = val.z; d[3] = val.w;
  }
  for (int u = t; u < 1536; u += 256) wbl[u] = Wb[u];
  for (int u = t; u < 192; u += 256) qi[u] = q[(size_t)i*192 + u];
  for (int u = t; u < 144; u += 256) qpi[u] = qpts[(size_t)i*144 + u];
  if (t < 12) {
    hwl[t] = log1pf(expf(head_w[t])) * 0.13608276348795434f; // softplus * sqrt(1/54)
    bbl[t] = bb[t];
  }
  __syncthreads();

  for (int item = t; item < 768; item += 256) {
    int h = item >> 6, jj = item & 63;
    int j = j0 + jj;
    const float* kp = kk + (size_t)j*192 + h*16;
    float qk = 0.f;
    #pragma unroll
    for (int c = 0; c < 16; c++) qk += qi[h*16 + c] * kp[c];
    float ptd = 0.f;
    const float* kpp = kvpts + ((size_t)j*144 + h*12)*3;
    #pragma unroll
    for (int p = 0; p < 4; p++) {
      #pragma unroll
      for (int x = 0; x < 3; x++) {
        float d = qpi[(h*4 + p)*3 + x] - kpp[p*3 + x];
        ptd += d*d;
      }
    }
    float bd = 0.f;
    const float* zr = zt + jj*129;
    for (int c = 0; c < 128; c++) bd += zr[c] * wbl[c*12 + h];
    float val = qk * 0.14433756729740643f
              + 0.5773502691896258f * (bd + bbl[h])
              - 0.5f * hwl[h] * ptd;
    a[((size_t)h*NN + i)*NN + j] = val;
  }
}

// ---------------------------------------------------------------------------
// K3: softmax over j for each (h,i) row; grid 9216 x 256
__global__ void k_softmax(float* __restrict__ a) {
  size_t row = blockIdx.x;
  float* p = a + row*NN;
  int t = threadIdx.x;
  float v0 = p[t], v1 = p[t+256], v2 = p[t+512];
  float m = fmaxf(fmaxf(v0, v1), v2);
  __shared__ float red[4];
  for (int off = 32; off; off >>= 1) m = fmaxf(m, __shfl_xor(m, off));
  int wid = t >> 6, lane = t & 63;
  if (lane == 0) red[wid] = m;
  __syncthreads();
  if (t == 0) {
    float mm = red[0];
    for (int w = 1; w < 4; w++) mm = fmaxf(mm, red[w]);
    red[0] = mm;
  }
  __syncthreads();
  m = red[0];
  float e0 = expf(v0 - m), e1 = expf(v1 - m), e2 = expf(v2 - m);
  float ssum = e0 + e1 + e2;
  for (int off = 32; off; off >>= 1) ssum += __shfl_xor(ssum, off);
  __shared__ float red2[4];
  if (lane == 0) red2[wid] = ssum;
  __syncthreads();
  if (t == 0) {
    float ss = 0.f;
    for (int w = 0; w < 4; w++) ss += red2[w];
    red2[0] = ss;
  }
  __syncthreads();
  float inv = 1.0f / red2[0];
  p[t] = e0*inv; p[t+256] = e1*inv; p[t+512] = e2*inv;
}

// ---------------------------------------------------------------------------
// K4: o = a@v ; o_pt = a@v_pts then inverse frame + norm. grid 768 x 320
__global__ void k_ov(const float* __restrict__ a, const float* __restrict__ vv,
                     const float* __restrict__ kvpts, const float* __restrict__ rot,
                     const float* __restrict__ trans, float* __restrict__ cat) {
  __shared__ float al[12][65];
  __shared__ float R[9];
  __shared__ float T[3];
  int i = blockIdx.x, t = threadIdx.x;
  if (t < 9) R[t] = rot[(size_t)i*9 + t];
  if (t < 3) T[t] = trans[(size_t)i*3 + t];
  float acc0 = 0.f, acc1 = 0.f, acc2 = 0.f;
  for (int jt = 0; jt < 12; jt++) {
    __syncthreads();
    for (int idx = t; idx < 768; idx += 320) {
      int h = idx >> 6, jj = idx & 63;
      al[h][jj] = a[((size_t)h*NN + i)*NN + jt*64 + jj];
    }
    __syncthreads();
    int j0 = jt * 64;
    if (t < 192) {
      int h = t >> 4;
      for (int jj = 0; jj < 64; jj++)
        acc0 += al[h][jj] * vv[(size_t)(j0+jj)*192 + t];
    } else if (t < 288) {
      int m = t - 192, h = m >> 3, p = m & 7;
      for (int jj = 0; jj < 64; jj++) {
        float w = al[h][jj];
        const float* vp = kvpts + ((size_t)(j0+jj)*144 + h*12 + 4 + p)*3;
        acc0 += w * vp[0]; acc1 += w * vp[1]; acc2 += w * vp[2];
      }
    }
  }
  if (t < 192) {
    cat[(size_t)i*CATC + t] = acc0;
  } else if (t < 288) {
    int m = t - 192;
    float x0 = acc0 - T[0], x1 = acc1 - T[1], x2 = acc2 - T[2];
    // inverse frame: out[x] = sum_y R[y][x] * (o[y]-T[y])
    float ox = R[0]*x0 + R[3]*x1 + R[6]*x2;
    float oy = R[1]*x0 + R[4]*x1 + R[7]*x2;
    float oz = R[2]*x0 + R[5]*x1 + R[8]*x2;
    float nrm = sqrtf(ox*ox + oy*oy + oz*oz + 1e-8f);
    float* c = cat + (size_t)i*CATC;
    c[192 + m] = ox; c[288 + m] = oy; c[384 + m] = oz; c[480 + m] = nrm;
  }
}

// ---------------------------------------------------------------------------
// K5: o_pair[i,h,c] = sum_j a[h,i,j]*z[i,j,c]. grid 768 x 256
__global__ void k_opair(const float* __restrict__ a, const float* __restrict__ z,
                        float* __restrict__ cat) {
  __shared__ float al[12][65];
  int i = blockIdx.x, t = threadIdx.x;
  int c = t & 127, hg = t >> 7;
  float acc[6] = {0.f,0.f,0.f,0.f,0.f,0.f};
  for (int jt = 0; jt < 12; jt++) {
    __syncthreads();
    for (int idx = t; idx < 768; idx += 256) {
      int h = idx >> 6, jj = idx & 63;
      al[h][jj] = a[((size_t)h*NN + i)*NN + jt*64 + jj];
    }
    __syncthreads();
    const float* zp = z + ((size_t)i*NN + jt*64)*CZ;
    for (int jj = 0; jj < 64; jj++) {
      float zv = zp[(size_t)jj*CZ + c];
      #pragma unroll
      for (int u = 0; u < 6; u++) acc[u] += al[hg + 2*u][jj] * zv;
    }
  }
  float* cc = cat + (size_t)i*CATC + 576;
  #pragma unroll
  for (int u = 0; u < 6; u++) cc[(hg + 2*u)*128 + c] = acc[u];
}

// ---------------------------------------------------------------------------
// K6: out = cat @ Wout + bout. grid 96 x 384, 8 rows of i per block
__global__ void k_out(const float* __restrict__ cat, const float* __restrict__ Wout,
                      const float* __restrict__ bout, float* __restrict__ out) {
  __shared__ float cl[8*CATC];
  int i0 = blockIdx.x*8, t = threadIdx.x;
  for (int idx = t; idx < 8*CATC; idx += 384) cl[idx] = cat[(size_t)i0*CATC + idx];
  __syncthreads();
  float acc[8] = {0.f,0.f,0.f,0.f,0.f,0.f,0.f,0.f};
  for (int r = 0; r < CATC; r++) {
    float w = Wout[(size_t)r*384 + t];
    #pragma unroll
    for (int g = 0; g < 8; g++) acc[g] += cl[g*CATC + r] * w;
  }
  float bo = bout[t];
  #pragma unroll
  for (int g = 0; g < 8; g++) out[(size_t)(i0+g)*384 + t] = acc[g] + bo;
}

// ---------------------------------------------------------------------------
extern "C" void kernel_launch(void* const* d_in, const int* in_sizes, int n_in,
                              void* d_out, int out_size, void* d_ws, size_t ws_size,
                              hipStream_t stream) {
  const float* s      = (const float*)d_in[0];
  const float* z      = (const float*)d_in[1];
  const float* rot    = (const float*)d_in[2];
  const float* trans  = (const float*)d_in[3];
  const float* Wq     = (const float*)d_in[4];
  const float* bq     = (const float*)d_in[5];
  const float* Wkv    = (const float*)d_in[6];
  const float* bkv    = (const float*)d_in[7];
  const float* Wqp    = (const float*)d_in[8];
  const float* bqp    = (const float*)d_in[9];
  const float* Wkvp   = (const float*)d_in[10];
  const float* bkvp   = (const float*)d_in[11];
  const float* Wb     = (const float*)d_in[12];
  const float* bb     = (const float*)d_in[13];
  const float* head_w = (const float*)d_in[14];
  const float* Wout   = (const float*)d_in[15];
  const float* bout   = (const float*)d_in[16];
  float* out = (float*)d_out;

  float* ws    = (float*)d_ws;
  float* q     = ws;                    // 768*192   = 147456
  float* kk    = q     + 147456;        // 147456
  float* vv    = kk    + 147456;        // 147456
  float* qpts  = vv    + 147456;        // 768*48*3  = 110592
  float* kvpts = qpts  + 110592;        // 768*144*3 = 331776
  float* a     = kvpts + 331776;        // 12*768*768= 7077888
  float* cat   = a     + 7077888;       // 768*2112  = 1622016

  k_proj<<<768, 256, 0, stream>>>(s, rot, trans, Wq, bq, Wkv, bkv, Wqp, bqp,
                                  Wkvp, bkvp, q, kk, vv, qpts, kvpts);
  k_logits<<<dim3(12, 768), 256, 0, stream>>>(q, kk, qpts, kvpts, z, Wb, bb, head_w, a);
  k_softmax<<<9216, 256, 0, stream>>>(a);
  k_ov<<<768, 320, 0, stream>>>(a, vv, kvpts, rot, trans, cat);
  k_opair<<<768, 256, 0, stream>>>(a, z, cat);
  k_out<<<96, 384, 0, stream>>>(cat, Wout, bout, out);
}

// Round 3
// 617.544 us; speedup vs baseline: 1.2587x; 1.2587x over previous
//
#include <hip/hip_runtime.h>
#include <hip/hip_bf16.h>
#include <cmath>

// Problem constants
#define NN 768
#define CS 384
#define CZ 128
#define CH 16
#define HH 12
#define PQ 4
#define PV 8
#define HC (HH*CH)          // 192
#define CATC 2112           // H*(CZ+CH+PV*4)

// ---------------------------------------------------------------------------
// K1: projections q,k,v,q_pts,kv_pts (with frame application)
// grid 768 blocks x 256 threads
__global__ void k_proj(const float* __restrict__ s, const float* __restrict__ rot,
                       const float* __restrict__ trans,
                       const float* __restrict__ Wq, const float* __restrict__ bq,
                       const float* __restrict__ Wkv, const float* __restrict__ bkv,
                       const float* __restrict__ Wqp, const float* __restrict__ bqp,
                       const float* __restrict__ Wkvp, const float* __restrict__ bkvp,
                       float* __restrict__ q, float* __restrict__ kk, float* __restrict__ vv,
                       float* __restrict__ qpts, float* __restrict__ kvpts) {
  __shared__ float srow[CS];
  __shared__ float rawq[144];
  __shared__ float rawkv[432];
  __shared__ float R[9];
  __shared__ float T[3];
  int n = blockIdx.x, t = threadIdx.x;
  for (int u = t; u < CS; u += 256) srow[u] = s[(size_t)n*CS + u];
  if (t < 9) R[t] = rot[(size_t)n*9 + t];
  if (t < 3) T[t] = trans[(size_t)n*3 + t];
  __syncthreads();

  for (int col = t; col < 192; col += 256) {
    float acc = bq[col];
    for (int c = 0; c < CS; c++) acc += srow[c] * Wq[(size_t)c*192 + col];
    q[(size_t)n*192 + col] = acc;
  }
  for (int col = t; col < 384; col += 256) {
    float acc = bkv[col];
    for (int c = 0; c < CS; c++) acc += srow[c] * Wkv[(size_t)c*384 + col];
    int h = col >> 5, u2 = col & 31;
    if (u2 < 16) kk[(size_t)n*192 + h*16 + u2] = acc;
    else         vv[(size_t)n*192 + h*16 + (u2-16)] = acc;
  }
  for (int col = t; col < 144; col += 256) {
    float acc = bqp[col];
    for (int c = 0; c < CS; c++) acc += srow[c] * Wqp[(size_t)c*144 + col];
    rawq[col] = acc;
  }
  for (int col = t; col < 432; col += 256) {
    float acc = bkvp[col];
    for (int c = 0; c < CS; c++) acc += srow[c] * Wkvp[(size_t)c*432 + col];
    rawkv[col] = acc;
  }
  __syncthreads();

  // apply frame: out[x] = sum_y R[x][y]*p[y] + T[x]; pts[m][y] = raw[y*M + m]
  for (int u = t; u < 48*3; u += 256) {
    int m = u / 3, x = u % 3;
    float p0 = rawq[0*48 + m], p1 = rawq[1*48 + m], p2 = rawq[2*48 + m];
    qpts[((size_t)n*48 + m)*3 + x] = R[x*3+0]*p0 + R[x*3+1]*p1 + R[x*3+2]*p2 + T[x];
  }
  for (int u = t; u < 144*3; u += 256) {
    int m = u / 3, x = u % 3;
    float p0 = rawkv[0*144 + m], p1 = rawkv[1*144 + m], p2 = rawkv[2*144 + m];
    kvpts[((size_t)n*144 + m)*3 + x] = R[x*3+0]*p0 + R[x*3+1]*p1 + R[x*3+2]*p2 + T[x];
  }
}

// ---------------------------------------------------------------------------
// K2: logits a[h,i,j] = qk*sqrt(1/48) + sqrt(1/3)*(z[i,j]@Wb[:,h]+bb[h])
//                      - 0.5*hw[h]*sum_p |qp-kp|^2
// grid (12 j-tiles, 768 i) x 256 threads; z tile staged in LDS (pad 129)
__global__ void k_logits(const float* __restrict__ q, const float* __restrict__ kk,
                         const float* __restrict__ qpts, const float* __restrict__ kvpts,
                         const float* __restrict__ z, const float* __restrict__ Wb,
                         const float* __restrict__ bb, const float* __restrict__ head_w,
                         float* __restrict__ a) {
  __shared__ float zt[64*129];
  __shared__ float wbl[128*12];
  __shared__ float qi[192];
  __shared__ float qpi[144];
  __shared__ float hwl[12];
  __shared__ float bbl[12];
  int i = blockIdx.y, jt = blockIdx.x, t = threadIdx.x;
  int j0 = jt * 64;
  const float4* zp = (const float4*)(z + ((size_t)i*NN + j0)*CZ);
  for (int u = t; u < 2048; u += 256) {
    float4 val = zp[u];
    int jj = u >> 5, cc = (u & 31) << 2;
    float* d = zt + jj*129 + cc;
    d[0] = val.x; d[1] = val.y; d[2] = val.z; d[3] = val.w;
  }
  for (int u = t; u < 1536; u += 256) wbl[u] = Wb[u];
  for (int u = t; u < 192; u += 256) qi[u] = q[(size_t)i*192 + u];
  for (int u = t; u < 144; u += 256) qpi[u] = qpts[(size_t)i*144 + u];
  if (t < 12) {
    hwl[t] = log1pf(expf(head_w[t])) * 0.13608276348795434f; // softplus * sqrt(1/54)
    bbl[t] = bb[t];
  }
  __syncthreads();

  for (int item = t; item < 768; item += 256) {
    int h = item >> 6, jj = item & 63;
    int j = j0 + jj;
    const float* kp = kk + (size_t)j*192 + h*16;
    float qk = 0.f;
    #pragma unroll
    for (int c = 0; c < 16; c++) qk += qi[h*16 + c] * kp[c];
    float ptd = 0.f;
    const float* kpp = kvpts + ((size_t)j*144 + h*12)*3;
    #pragma unroll
    for (int p = 0; p < 4; p++) {
      #pragma unroll
      for (int x = 0; x < 3; x++) {
        float d = qpi[(h*4 + p)*3 + x] - kpp[p*3 + x];
        ptd += d*d;
      }
    }
    float bd = 0.f;
    const float* zr = zt + jj*129;
    for (int c = 0; c < 128; c++) bd += zr[c] * wbl[c*12 + h];
    float val = qk * 0.14433756729740643f
              + 0.5773502691896258f * (bd + bbl[h])
              - 0.5f * hwl[h] * ptd;
    a[((size_t)h*NN + i)*NN + j] = val;
  }
}

// ---------------------------------------------------------------------------
// K3: softmax over j for each (h,i) row; grid 9216 x 256
__global__ void k_softmax(float* __restrict__ a) {
  size_t row = blockIdx.x;
  float* p = a + row*NN;
  int t = threadIdx.x;
  float v0 = p[t], v1 = p[t+256], v2 = p[t+512];
  float m = fmaxf(fmaxf(v0, v1), v2);
  __shared__ float red[4];
  for (int off = 32; off; off >>= 1) m = fmaxf(m, __shfl_xor(m, off));
  int wid = t >> 6, lane = t & 63;
  if (lane == 0) red[wid] = m;
  __syncthreads();
  if (t == 0) {
    float mm = red[0];
    for (int w = 1; w < 4; w++) mm = fmaxf(mm, red[w]);
    red[0] = mm;
  }
  __syncthreads();
  m = red[0];
  float e0 = expf(v0 - m), e1 = expf(v1 - m), e2 = expf(v2 - m);
  float ssum = e0 + e1 + e2;
  for (int off = 32; off; off >>= 1) ssum += __shfl_xor(ssum, off);
  __shared__ float red2[4];
  if (lane == 0) red2[wid] = ssum;
  __syncthreads();
  if (t == 0) {
    float ss = 0.f;
    for (int w = 0; w < 4; w++) ss += red2[w];
    red2[0] = ss;
  }
  __syncthreads();
  float inv = 1.0f / red2[0];
  p[t] = e0*inv; p[t+256] = e1*inv; p[t+512] = e2*inv;
}

// ---------------------------------------------------------------------------
// K4: o = a@v ; o_pt = a@v_pts then inverse frame + norm. grid 768 x 320
__global__ void k_ov(const float* __restrict__ a, const float* __restrict__ vv,
                     const float* __restrict__ kvpts, const float* __restrict__ rot,
                     const float* __restrict__ trans, float* __restrict__ cat) {
  __shared__ float al[12][65];
  __shared__ float R[9];
  __shared__ float T[3];
  int i = blockIdx.x, t = threadIdx.x;
  if (t < 9) R[t] = rot[(size_t)i*9 + t];
  if (t < 3) T[t] = trans[(size_t)i*3 + t];
  float acc0 = 0.f, acc1 = 0.f, acc2 = 0.f;
  for (int jt = 0; jt < 12; jt++) {
    __syncthreads();
    for (int idx = t; idx < 768; idx += 320) {
      int h = idx >> 6, jj = idx & 63;
      al[h][jj] = a[((size_t)h*NN + i)*NN + jt*64 + jj];
    }
    __syncthreads();
    int j0 = jt * 64;
    if (t < 192) {
      int h = t >> 4;
      for (int jj = 0; jj < 64; jj++)
        acc0 += al[h][jj] * vv[(size_t)(j0+jj)*192 + t];
    } else if (t < 288) {
      int m = t - 192, h = m >> 3, p = m & 7;
      for (int jj = 0; jj < 64; jj++) {
        float w = al[h][jj];
        const float* vp = kvpts + ((size_t)(j0+jj)*144 + h*12 + 4 + p)*3;
        acc0 += w * vp[0]; acc1 += w * vp[1]; acc2 += w * vp[2];
      }
    }
  }
  if (t < 192) {
    cat[(size_t)i*CATC + t] = acc0;
  } else if (t < 288) {
    int m = t - 192;
    float x0 = acc0 - T[0], x1 = acc1 - T[1], x2 = acc2 - T[2];
    // inverse frame: out[x] = sum_y R[y][x] * (o[y]-T[y])
    float ox = R[0]*x0 + R[3]*x1 + R[6]*x2;
    float oy = R[1]*x0 + R[4]*x1 + R[7]*x2;
    float oz = R[2]*x0 + R[5]*x1 + R[8]*x2;
    float nrm = sqrtf(ox*ox + oy*oy + oz*oz + 1e-8f);
    float* c = cat + (size_t)i*CATC;
    c[192 + m] = ox; c[288 + m] = oy; c[384 + m] = oz; c[480 + m] = nrm;
  }
}

// ---------------------------------------------------------------------------
// K5: o_pair[i,h,c] = sum_j a[h,i,j]*z[i,j,c]. grid 768 x 256
__global__ void k_opair(const float* __restrict__ a, const float* __restrict__ z,
                        float* __restrict__ cat) {
  __shared__ float al[12][65];
  int i = blockIdx.x, t = threadIdx.x;
  int c = t & 127, hg = t >> 7;
  float acc[6] = {0.f,0.f,0.f,0.f,0.f,0.f};
  for (int jt = 0; jt < 12; jt++) {
    __syncthreads();
    for (int idx = t; idx < 768; idx += 256) {
      int h = idx >> 6, jj = idx & 63;
      al[h][jj] = a[((size_t)h*NN + i)*NN + jt*64 + jj];
    }
    __syncthreads();
    const float* zp = z + ((size_t)i*NN + jt*64)*CZ;
    for (int jj = 0; jj < 64; jj++) {
      float zv = zp[(size_t)jj*CZ + c];
      #pragma unroll
      for (int u = 0; u < 6; u++) acc[u] += al[hg + 2*u][jj] * zv;
    }
  }
  float* cc = cat + (size_t)i*CATC + 576;
  #pragma unroll
  for (int u = 0; u < 6; u++) cc[(hg + 2*u)*128 + c] = acc[u];
}

// ---------------------------------------------------------------------------
// K6: out = cat @ Wout + bout.
// v2: ROWS=3 per block -> grid 256 (1 block/CU, all CUs busy), r-loop
// unrolled x8 so each wave keeps 8 independent L2 loads in flight.
// cl[] operand is wave-uniform -> LDS broadcast (conflict-free).
#define OROWS 3
__global__ void k_out(const float* __restrict__ cat, const float* __restrict__ Wout,
                      const float* __restrict__ bout, float* __restrict__ out) {
  __shared__ float cl[OROWS*CATC];
  int i0 = blockIdx.x*OROWS, t = threadIdx.x;
  for (int idx = t; idx < OROWS*CATC; idx += 384) cl[idx] = cat[(size_t)i0*CATC + idx];
  __syncthreads();
  float acc[OROWS];
  #pragma unroll
  for (int g = 0; g < OROWS; g++) acc[g] = 0.f;
  for (int r = 0; r < CATC; r += 8) {
    float w[8];
    #pragma unroll
    for (int u = 0; u < 8; u++) w[u] = Wout[(size_t)(r+u)*384 + t];
    #pragma unroll
    for (int u = 0; u < 8; u++) {
      #pragma unroll
      for (int g = 0; g < OROWS; g++) acc[g] += cl[g*CATC + r + u] * w[u];
    }
  }
  float bo = bout[t];
  #pragma unroll
  for (int g = 0; g < OROWS; g++) out[(size_t)(i0+g)*384 + t] = acc[g] + bo;
}

// ---------------------------------------------------------------------------
extern "C" void kernel_launch(void* const* d_in, const int* in_sizes, int n_in,
                              void* d_out, int out_size, void* d_ws, size_t ws_size,
                              hipStream_t stream) {
  const float* s      = (const float*)d_in[0];
  const float* z      = (const float*)d_in[1];
  const float* rot    = (const float*)d_in[2];
  const float* trans  = (const float*)d_in[3];
  const float* Wq     = (const float*)d_in[4];
  const float* bq     = (const float*)d_in[5];
  const float* Wkv    = (const float*)d_in[6];
  const float* bkv    = (const float*)d_in[7];
  const float* Wqp    = (const float*)d_in[8];
  const float* bqp    = (const float*)d_in[9];
  const float* Wkvp   = (const float*)d_in[10];
  const float* bkvp   = (const float*)d_in[11];
  const float* Wb     = (const float*)d_in[12];
  const float* bb     = (const float*)d_in[13];
  const float* head_w = (const float*)d_in[14];
  const float* Wout   = (const float*)d_in[15];
  const float* bout   = (const float*)d_in[16];
  float* out = (float*)d_out;

  float* ws    = (float*)d_ws;
  float* q     = ws;                    // 768*192   = 147456
  float* kk    = q     + 147456;        // 147456
  float* vv    = kk    + 147456;        // 147456
  float* qpts  = vv    + 147456;        // 768*48*3  = 110592
  float* kvpts = qpts  + 110592;        // 768*144*3 = 331776
  float* a     = kvpts + 331776;        // 12*768*768= 7077888
  float* cat   = a     + 7077888;       // 768*2112  = 1622016

  k_proj<<<768, 256, 0, stream>>>(s, rot, trans, Wq, bq, Wkv, bkv, Wqp, bqp,
                                  Wkvp, bkvp, q, kk, vv, qpts, kvpts);
  k_logits<<<dim3(12, 768), 256, 0, stream>>>(q, kk, qpts, kvpts, z, Wb, bb, head_w, a);
  k_softmax<<<9216, 256, 0, stream>>>(a);
  k_ov<<<768, 320, 0, stream>>>(a, vv, kvpts, rot, trans, cat);
  k_opair<<<768, 256, 0, stream>>>(a, z, cat);
  k_out<<<256, 384, 0, stream>>>(cat, Wout, bout, out);
}

// Round 4
// 578.228 us; speedup vs baseline: 1.3443x; 1.0680x over previous
//
#include <hip/hip_runtime.h>
#include <hip/hip_bf16.h>
#include <cmath>

// Problem constants
#define NN 768
#define CS 384
#define CZ 128
#define CH 16
#define HH 12
#define PQ 4
#define PV 8
#define CATC 2112           // H*(CZ+CH+PV*4)

typedef __attribute__((ext_vector_type(8))) __bf16 bf16x8;
typedef __attribute__((ext_vector_type(8))) unsigned short us8;
typedef __attribute__((ext_vector_type(4))) float f32x4;

__device__ __forceinline__ unsigned short f2bf(float f) {
  unsigned int u = __builtin_bit_cast(unsigned int, f);
  u += 0x7FFFu + ((u >> 16) & 1u);   // RNE
  return (unsigned short)(u >> 16);
}
__device__ __forceinline__ float bf2f(unsigned short u) {
  return __builtin_bit_cast(float, ((unsigned int)u) << 16);
}

// ---------------------------------------------------------------------------
// K1: projections q,k,v,q_pts,kv_pts (with frame application)
// grid 768 blocks x 256 threads
__global__ void k_proj(const float* __restrict__ s, const float* __restrict__ rot,
                       const float* __restrict__ trans,
                       const float* __restrict__ Wq, const float* __restrict__ bq,
                       const float* __restrict__ Wkv, const float* __restrict__ bkv,
                       const float* __restrict__ Wqp, const float* __restrict__ bqp,
                       const float* __restrict__ Wkvp, const float* __restrict__ bkvp,
                       float* __restrict__ q, float* __restrict__ kk, float* __restrict__ vv,
                       float* __restrict__ qpts, float* __restrict__ kvpts) {
  __shared__ float srow[CS];
  __shared__ float rawq[144];
  __shared__ float rawkv[432];
  __shared__ float R[9];
  __shared__ float T[3];
  int n = blockIdx.x, t = threadIdx.x;
  for (int u = t; u < CS; u += 256) srow[u] = s[(size_t)n*CS + u];
  if (t < 9) R[t] = rot[(size_t)n*9 + t];
  if (t < 3) T[t] = trans[(size_t)n*3 + t];
  __syncthreads();

  for (int col = t; col < 192; col += 256) {
    float acc = bq[col];
    for (int c = 0; c < CS; c++) acc += srow[c] * Wq[(size_t)c*192 + col];
    q[(size_t)n*192 + col] = acc;
  }
  for (int col = t; col < 384; col += 256) {
    float acc = bkv[col];
    for (int c = 0; c < CS; c++) acc += srow[c] * Wkv[(size_t)c*384 + col];
    int h = col >> 5, u2 = col & 31;
    if (u2 < 16) kk[(size_t)n*192 + h*16 + u2] = acc;
    else         vv[(size_t)n*192 + h*16 + (u2-16)] = acc;
  }
  for (int col = t; col < 144; col += 256) {
    float acc = bqp[col];
    for (int c = 0; c < CS; c++) acc += srow[c] * Wqp[(size_t)c*144 + col];
    rawq[col] = acc;
  }
  for (int col = t; col < 432; col += 256) {
    float acc = bkvp[col];
    for (int c = 0; c < CS; c++) acc += srow[c] * Wkvp[(size_t)c*432 + col];
    rawkv[col] = acc;
  }
  __syncthreads();

  for (int u = t; u < 48*3; u += 256) {
    int m = u / 3, x = u % 3;
    float p0 = rawq[0*48 + m], p1 = rawq[1*48 + m], p2 = rawq[2*48 + m];
    qpts[((size_t)n*48 + m)*3 + x] = R[x*3+0]*p0 + R[x*3+1]*p1 + R[x*3+2]*p2 + T[x];
  }
  for (int u = t; u < 144*3; u += 256) {
    int m = u / 3, x = u % 3;
    float p0 = rawkv[0*144 + m], p1 = rawkv[1*144 + m], p2 = rawkv[2*144 + m];
    kvpts[((size_t)n*144 + m)*3 + x] = R[x*3+0]*p0 + R[x*3+1]*p1 + R[x*3+2]*p2 + T[x];
  }
}

// ---------------------------------------------------------------------------
// K2 (MFMA): logits a[i][h][j].  b^T via mfma_f32_16x16x32_bf16:
//   A = Wb^T  (M=16 h-rows, K=128 c)  -- registers, lane: row=l&15, k=(l>>4)*8+e
//   B = z^T   (K=128 c,  N=64 j)      -- global float4 -> bf16, col=l&15
//   C: row=(l>>4)*4+reg = h, col=l&15 = j  -> coalesced a-stores
// grid (12 jt, 768 i) x 256 (4 waves, one 16-j N-tile each). z read ONCE.
__global__ void k_logits(const float* __restrict__ q, const float* __restrict__ kkv,
                         const float* __restrict__ qpts, const float* __restrict__ kvpts,
                         const float* __restrict__ z, const float* __restrict__ Wb,
                         const float* __restrict__ bb, const float* __restrict__ head_w,
                         float* __restrict__ a) {
  __shared__ float qi[192];
  __shared__ float qpi[144];
  int jt = blockIdx.x, i = blockIdx.y, t = threadIdx.x;
  int w = t >> 6, l = t & 63, kg = l >> 4, l15 = l & 15;
  int j0 = jt * 64;
  for (int u = t; u < 192; u += 256) qi[u] = q[(size_t)i*192 + u];
  for (int u = t; u < 144; u += 256) qpi[u] = qpts[(size_t)i*144 + u];

  // A-frags: Wb^T, 4 K-steps
  us8 af[4];
  #pragma unroll
  for (int ks = 0; ks < 4; ks++) {
    #pragma unroll
    for (int kc = 0; kc < 8; kc++) {
      af[ks][kc] = (l15 < 12) ? f2bf(Wb[(size_t)(ks*32 + kg*8 + kc)*12 + l15])
                              : (unsigned short)0;
    }
  }
  __syncthreads();

  int jcol = j0 + w*16 + l15;
  const float* zr = z + ((size_t)i*NN + jcol)*CZ;
  f32x4 acc = {0.f, 0.f, 0.f, 0.f};
  #pragma unroll
  for (int ks = 0; ks < 4; ks++) {
    float4 z0 = *(const float4*)(zr + ks*32 + kg*8);
    float4 z1 = *(const float4*)(zr + ks*32 + kg*8 + 4);
    us8 bv;
    bv[0] = f2bf(z0.x); bv[1] = f2bf(z0.y); bv[2] = f2bf(z0.z); bv[3] = f2bf(z0.w);
    bv[4] = f2bf(z1.x); bv[5] = f2bf(z1.y); bv[6] = f2bf(z1.z); bv[7] = f2bf(z1.w);
    acc = __builtin_amdgcn_mfma_f32_16x16x32_bf16(
        __builtin_bit_cast(bf16x8, af[ks]), __builtin_bit_cast(bf16x8, bv), acc, 0, 0, 0);
  }

  // epilogue: qk + point term per (h = kg*4+r, j = jcol)
  const float4* kj4 = (const float4*)(kkv + (size_t)jcol*192);
  const float4* kp4 = (const float4*)(kvpts + (size_t)jcol*432);
  #pragma unroll
  for (int r = 0; r < 4; r++) {
    int h = kg*4 + r;
    if (h < 12) {
      const float* qh = qi + h*16;
      float4 k0 = kj4[h*4+0], k1 = kj4[h*4+1], k2 = kj4[h*4+2], k3 = kj4[h*4+3];
      float qk = qh[0]*k0.x + qh[1]*k0.y + qh[2]*k0.z + qh[3]*k0.w
               + qh[4]*k1.x + qh[5]*k1.y + qh[6]*k1.z + qh[7]*k1.w
               + qh[8]*k2.x + qh[9]*k2.y + qh[10]*k2.z + qh[11]*k2.w
               + qh[12]*k3.x + qh[13]*k3.y + qh[14]*k3.z + qh[15]*k3.w;
      const float* qp = qpi + h*12;
      float4 p0 = kp4[h*9+0], p1 = kp4[h*9+1], p2 = kp4[h*9+2];
      float d, ptd = 0.f;
      d = qp[0]-p0.x; ptd += d*d;  d = qp[1]-p0.y; ptd += d*d;
      d = qp[2]-p0.z; ptd += d*d;  d = qp[3]-p0.w; ptd += d*d;
      d = qp[4]-p1.x; ptd += d*d;  d = qp[5]-p1.y; ptd += d*d;
      d = qp[6]-p1.z; ptd += d*d;  d = qp[7]-p1.w; ptd += d*d;
      d = qp[8]-p2.x; ptd += d*d;  d = qp[9]-p2.y; ptd += d*d;
      d = qp[10]-p2.z; ptd += d*d; d = qp[11]-p2.w; ptd += d*d;
      float hw = log1pf(expf(head_w[h])) * 0.13608276348795434f; // softplus*sqrt(1/54)
      float val = 0.5773502691896258f * (acc[r] + bb[h])
                + 0.14433756729740643f * qk
                - 0.5f * hw * ptd;
      a[((size_t)i*12 + h)*768 + jcol] = val;
    }
  }
}

// ---------------------------------------------------------------------------
// K3: softmax over j for each (i,h) row; reads fp32 logits, writes bf16 probs
__global__ void k_softmax(const float* __restrict__ a, unsigned short* __restrict__ p_bf) {
  size_t row = blockIdx.x;
  const float* p = a + row*NN;
  int t = threadIdx.x;
  float v0 = p[t], v1 = p[t+256], v2 = p[t+512];
  float m = fmaxf(fmaxf(v0, v1), v2);
  __shared__ float red[4];
  for (int off = 32; off; off >>= 1) m = fmaxf(m, __shfl_xor(m, off));
  int wid = t >> 6, lane = t & 63;
  if (lane == 0) red[wid] = m;
  __syncthreads();
  if (t == 0) {
    float mm = red[0];
    for (int w = 1; w < 4; w++) mm = fmaxf(mm, red[w]);
    red[0] = mm;
  }
  __syncthreads();
  m = red[0];
  float e0 = expf(v0 - m), e1 = expf(v1 - m), e2 = expf(v2 - m);
  float ssum = e0 + e1 + e2;
  for (int off = 32; off; off >>= 1) ssum += __shfl_xor(ssum, off);
  __shared__ float red2[4];
  if (lane == 0) red2[wid] = ssum;
  __syncthreads();
  if (t == 0) {
    float ss = 0.f;
    for (int w = 0; w < 4; w++) ss += red2[w];
    red2[0] = ss;
  }
  __syncthreads();
  float inv = 1.0f / red2[0];
  unsigned short* o = p_bf + row*NN;
  o[t]     = f2bf(e0*inv);
  o[t+256] = f2bf(e1*inv);
  o[t+512] = f2bf(e2*inv);
}

// ---------------------------------------------------------------------------
// K4: o = p@v ; o_pt = p@v_pts then inverse frame + norm. grid 768 x 320
__global__ void k_ov(const unsigned short* __restrict__ p_bf, const float* __restrict__ vv,
                     const float* __restrict__ kvpts, const float* __restrict__ rot,
                     const float* __restrict__ trans, float* __restrict__ cat) {
  __shared__ float al[12][65];
  __shared__ float R[9];
  __shared__ float T[3];
  int i = blockIdx.x, t = threadIdx.x;
  if (t < 9) R[t] = rot[(size_t)i*9 + t];
  if (t < 3) T[t] = trans[(size_t)i*3 + t];
  float acc0 = 0.f, acc1 = 0.f, acc2 = 0.f;
  for (int jt = 0; jt < 12; jt++) {
    __syncthreads();
    for (int idx = t; idx < 768; idx += 320) {
      int h = idx >> 6, jj = idx & 63;
      al[h][jj] = bf2f(p_bf[((size_t)i*12 + h)*768 + jt*64 + jj]);
    }
    __syncthreads();
    int j0 = jt * 64;
    if (t < 192) {
      int h = t >> 4;
      for (int jj = 0; jj < 64; jj++)
        acc0 += al[h][jj] * vv[(size_t)(j0+jj)*192 + t];
    } else if (t < 288) {
      int m = t - 192, h = m >> 3, pp = m & 7;
      for (int jj = 0; jj < 64; jj++) {
        float wgt = al[h][jj];
        const float* vp = kvpts + ((size_t)(j0+jj)*144 + h*12 + 4 + pp)*3;
        acc0 += wgt * vp[0]; acc1 += wgt * vp[1]; acc2 += wgt * vp[2];
      }
    }
  }
  if (t < 192) {
    cat[(size_t)i*CATC + t] = acc0;
  } else if (t < 288) {
    int m = t - 192;
    float x0 = acc0 - T[0], x1 = acc1 - T[1], x2 = acc2 - T[2];
    float ox = R[0]*x0 + R[3]*x1 + R[6]*x2;
    float oy = R[1]*x0 + R[4]*x1 + R[7]*x2;
    float oz = R[2]*x0 + R[5]*x1 + R[8]*x2;
    float nrm = sqrtf(ox*ox + oy*oy + oz*oz + 1e-8f);
    float* c = cat + (size_t)i*CATC;
    c[192 + m] = ox; c[288 + m] = oy; c[384 + m] = oz; c[480 + m] = nrm;
  }
}

// ---------------------------------------------------------------------------
// K5 (MFMA): o_pair[i][h][c] = sum_j p[h][j] z[i][j][c].
//   A = p (M=16 h, K=768 j) bf16 direct 16B loads; B = z (K, N=128) f32->bf16.
//   4 waves x 2 N-tiles; 24 K-steps of 32 j. z read ONCE. grid 768 x 256.
__global__ void k_opair(const unsigned short* __restrict__ p_bf,
                        const float* __restrict__ z, float* __restrict__ cat) {
  int i = blockIdx.x, t = threadIdx.x;
  int w = t >> 6, l = t & 63, kg = l >> 4, l15 = l & 15;
  int cb = w * 32;
  f32x4 acc0 = {0.f,0.f,0.f,0.f}, acc1 = {0.f,0.f,0.f,0.f};
  const unsigned short* prow = p_bf + ((size_t)i*12 + l15)*768 + kg*8;
  const float* zb = z + (size_t)i*NN*CZ;
  for (int ks = 0; ks < 24; ks++) {
    int j0 = ks * 32;
    us8 av;
    if (l15 < 12) {
      av = *(const us8*)(prow + j0);
    } else {
      av = (us8){0,0,0,0,0,0,0,0};
    }
    const float* zq = zb + (size_t)(j0 + kg*8)*CZ + cb + l15;
    us8 b0, b1;
    #pragma unroll
    for (int kc = 0; kc < 8; kc++) {
      b0[kc] = f2bf(zq[(size_t)kc*CZ]);
      b1[kc] = f2bf(zq[(size_t)kc*CZ + 16]);
    }
    acc0 = __builtin_amdgcn_mfma_f32_16x16x32_bf16(
        __builtin_bit_cast(bf16x8, av), __builtin_bit_cast(bf16x8, b0), acc0, 0, 0, 0);
    acc1 = __builtin_amdgcn_mfma_f32_16x16x32_bf16(
        __builtin_bit_cast(bf16x8, av), __builtin_bit_cast(bf16x8, b1), acc1, 0, 0, 0);
  }
  #pragma unroll
  for (int r = 0; r < 4; r++) {
    int h = kg*4 + r;
    if (h < 12) {
      float* cc = cat + (size_t)i*CATC + 576 + (size_t)h*128;
      cc[cb + l15]      = acc0[r];
      cc[cb + 16 + l15] = acc1[r];
    }
  }
}

// ---------------------------------------------------------------------------
// K6: out = cat @ Wout + bout. ROWS=3/block -> grid 256, x8-unrolled loads.
#define OROWS 3
__global__ void k_out(const float* __restrict__ cat, const float* __restrict__ Wout,
                      const float* __restrict__ bout, float* __restrict__ out) {
  __shared__ float cl[OROWS*CATC];
  int i0 = blockIdx.x*OROWS, t = threadIdx.x;
  for (int idx = t; idx < OROWS*CATC; idx += 384) cl[idx] = cat[(size_t)i0*CATC + idx];
  __syncthreads();
  float acc[OROWS];
  #pragma unroll
  for (int g = 0; g < OROWS; g++) acc[g] = 0.f;
  for (int r = 0; r < CATC; r += 8) {
    float wv[8];
    #pragma unroll
    for (int u = 0; u < 8; u++) wv[u] = Wout[(size_t)(r+u)*384 + t];
    #pragma unroll
    for (int u = 0; u < 8; u++) {
      #pragma unroll
      for (int g = 0; g < OROWS; g++) acc[g] += cl[g*CATC + r + u] * wv[u];
    }
  }
  float bo = bout[t];
  #pragma unroll
  for (int g = 0; g < OROWS; g++) out[(size_t)(i0+g)*384 + t] = acc[g] + bo;
}

// ---------------------------------------------------------------------------
extern "C" void kernel_launch(void* const* d_in, const int* in_sizes, int n_in,
                              void* d_out, int out_size, void* d_ws, size_t ws_size,
                              hipStream_t stream) {
  const float* s      = (const float*)d_in[0];
  const float* z      = (const float*)d_in[1];
  const float* rot    = (const float*)d_in[2];
  const float* trans  = (const float*)d_in[3];
  const float* Wq     = (const float*)d_in[4];
  const float* bq     = (const float*)d_in[5];
  const float* Wkv    = (const float*)d_in[6];
  const float* bkv    = (const float*)d_in[7];
  const float* Wqp    = (const float*)d_in[8];
  const float* bqp    = (const float*)d_in[9];
  const float* Wkvp   = (const float*)d_in[10];
  const float* bkvp   = (const float*)d_in[11];
  const float* Wb     = (const float*)d_in[12];
  const float* bb     = (const float*)d_in[13];
  const float* head_w = (const float*)d_in[14];
  const float* Wout   = (const float*)d_in[15];
  const float* bout   = (const float*)d_in[16];
  float* out = (float*)d_out;

  float* ws    = (float*)d_ws;
  float* q     = ws;                    // 147456
  float* kk    = q     + 147456;        // 147456
  float* vv    = kk    + 147456;        // 147456
  float* qpts  = vv    + 147456;        // 110592
  float* kvpts = qpts  + 110592;        // 331776
  float* a     = kvpts + 331776;        // 7077888  [i][h][j] fp32 logits
  unsigned short* p_bf = (unsigned short*)(a + 7077888);  // 7077888 bf16 probs
  float* cat   = (float*)(p_bf + 7077888);                // 1622016

  k_proj<<<768, 256, 0, stream>>>(s, rot, trans, Wq, bq, Wkv, bkv, Wqp, bqp,
                                  Wkvp, bkvp, q, kk, vv, qpts, kvpts);
  k_logits<<<dim3(12, 768), 256, 0, stream>>>(q, kk, qpts, kvpts, z, Wb, bb, head_w, a);
  k_softmax<<<9216, 256, 0, stream>>>(a, p_bf);
  k_ov<<<768, 320, 0, stream>>>(p_bf, vv, kvpts, rot, trans, cat);
  k_opair<<<768, 256, 0, stream>>>(p_bf, z, cat);
  k_out<<<256, 384, 0, stream>>>(cat, Wout, bout, out);
}

// Round 5
// 526.814 us; speedup vs baseline: 1.4755x; 1.0976x over previous
//
#include <hip/hip_runtime.h>
#include <hip/hip_bf16.h>
#include <cmath>

// Problem constants
#define NN 768
#define CS 384
#define CZ 128
#define CH 16
#define HH 12
#define PQ 4
#define PV 8
#define CATC 2112           // H*(CZ+CH+PV*4)

typedef __attribute__((ext_vector_type(8))) __bf16 bf16x8;
typedef __attribute__((ext_vector_type(8))) unsigned short us8;
typedef __attribute__((ext_vector_type(4))) float f32x4;

__device__ __forceinline__ unsigned short f2bf(float f) {
  unsigned int u = __builtin_bit_cast(unsigned int, f);
  u += 0x7FFFu + ((u >> 16) & 1u);   // RNE
  return (unsigned short)(u >> 16);
}
__device__ __forceinline__ float bf2f(unsigned short u) {
  return __builtin_bit_cast(float, ((unsigned int)u) << 16);
}

// ---------------------------------------------------------------------------
// K1: projections q,k,v,q_pts,kv_pts (with frame application)
// grid 768 blocks x 256 threads
__global__ void k_proj(const float* __restrict__ s, const float* __restrict__ rot,
                       const float* __restrict__ trans,
                       const float* __restrict__ Wq, const float* __restrict__ bq,
                       const float* __restrict__ Wkv, const float* __restrict__ bkv,
                       const float* __restrict__ Wqp, const float* __restrict__ bqp,
                       const float* __restrict__ Wkvp, const float* __restrict__ bkvp,
                       float* __restrict__ q, float* __restrict__ kk, float* __restrict__ vv,
                       float* __restrict__ qpts, float* __restrict__ kvpts) {
  __shared__ float srow[CS];
  __shared__ float rawq[144];
  __shared__ float rawkv[432];
  __shared__ float R[9];
  __shared__ float T[3];
  int n = blockIdx.x, t = threadIdx.x;
  for (int u = t; u < CS; u += 256) srow[u] = s[(size_t)n*CS + u];
  if (t < 9) R[t] = rot[(size_t)n*9 + t];
  if (t < 3) T[t] = trans[(size_t)n*3 + t];
  __syncthreads();

  for (int col = t; col < 192; col += 256) {
    float acc = bq[col];
    for (int c = 0; c < CS; c++) acc += srow[c] * Wq[(size_t)c*192 + col];
    q[(size_t)n*192 + col] = acc;
  }
  for (int col = t; col < 384; col += 256) {
    float acc = bkv[col];
    for (int c = 0; c < CS; c++) acc += srow[c] * Wkv[(size_t)c*384 + col];
    int h = col >> 5, u2 = col & 31;
    if (u2 < 16) kk[(size_t)n*192 + h*16 + u2] = acc;
    else         vv[(size_t)n*192 + h*16 + (u2-16)] = acc;
  }
  for (int col = t; col < 144; col += 256) {
    float acc = bqp[col];
    for (int c = 0; c < CS; c++) acc += srow[c] * Wqp[(size_t)c*144 + col];
    rawq[col] = acc;
  }
  for (int col = t; col < 432; col += 256) {
    float acc = bkvp[col];
    for (int c = 0; c < CS; c++) acc += srow[c] * Wkvp[(size_t)c*432 + col];
    rawkv[col] = acc;
  }
  __syncthreads();

  for (int u = t; u < 48*3; u += 256) {
    int m = u / 3, x = u % 3;
    float p0 = rawq[0*48 + m], p1 = rawq[1*48 + m], p2 = rawq[2*48 + m];
    qpts[((size_t)n*48 + m)*3 + x] = R[x*3+0]*p0 + R[x*3+1]*p1 + R[x*3+2]*p2 + T[x];
  }
  for (int u = t; u < 144*3; u += 256) {
    int m = u / 3, x = u % 3;
    float p0 = rawkv[0*144 + m], p1 = rawkv[1*144 + m], p2 = rawkv[2*144 + m];
    kvpts[((size_t)n*144 + m)*3 + x] = R[x*3+0]*p0 + R[x*3+1]*p1 + R[x*3+2]*p2 + T[x];
  }
}

// ---------------------------------------------------------------------------
// K_prep: augmented B matrix for logits, bf16, swizzled for coalesced us8 frags.
// augB[j][h][cc]: cc<16 -> k[j,h,cc]; cc in 16..27 -> k_pts[j,h,p,x] (p*3+x);
// cc==28 -> |k_pts[j,h]|^2; cc==29 -> 1; cc 30,31 -> 0.
// Stored as Bq[jtile=j>>4][h][kg=cc>>3][l15=j&15][e=cc&7] (us8 granularity).
// grid 48 x 256
__global__ void k_prep(const float* __restrict__ kk, const float* __restrict__ kvpts,
                       unsigned short* __restrict__ Bq) {
  int jt16 = blockIdx.x, t = threadIdx.x;
  for (int u = t; u < 768; u += 256) {
    int hp = u >> 6, kg = (u >> 4) & 3, l15 = u & 15;
    int j = jt16*16 + l15;
    unsigned short vals[8];
    #pragma unroll
    for (int e = 0; e < 8; e++) {
      int cc = kg*8 + e;
      float v;
      if (cc < 16) {
        v = kk[(size_t)j*192 + hp*16 + cc];
      } else if (cc < 28) {
        v = kvpts[(size_t)j*432 + hp*36 + (cc-16)];
      } else if (cc == 28) {
        float s2 = 0.f;
        #pragma unroll
        for (int m = 0; m < 12; m++) {
          float d = kvpts[(size_t)j*432 + hp*36 + m];
          s2 += d*d;
        }
        v = s2;
      } else if (cc == 29) {
        v = 1.0f;
      } else {
        v = 0.f;
      }
      vals[e] = f2bf(v);
    }
    *(us8*)(Bq + ((size_t)(jt16*12 + hp)*64 + kg*16 + l15)*8) = *(const us8*)vals;
  }
}

// ---------------------------------------------------------------------------
// K2 (pure MFMA): a[i][h][j] = [sc3*Wb^T | augA] x [z^T | augB].
// K = 128 (z) + 12*32 (block-diagonal aug per head) = 16 MFMA per 16-j tile.
// No per-(h,j) epilogue loads at all. grid (12 jt, 768 i) x 256.
__global__ void k_logits(const float* __restrict__ q, const float* __restrict__ qpts,
                         const float* __restrict__ z, const float* __restrict__ Wb,
                         const float* __restrict__ bb, const float* __restrict__ head_w,
                         const unsigned short* __restrict__ Bq, float* __restrict__ a) {
  __shared__ float qi[192];
  __shared__ float qpi[144];
  int jt = blockIdx.x, i = blockIdx.y, t = threadIdx.x;
  int w = t >> 6, l = t & 63, kg = l >> 4, l15 = l & 15;
  for (int u = t; u < 192; u += 256) qi[u] = q[(size_t)i*192 + u];
  for (int u = t; u < 144; u += 256) qpi[u] = qpts[(size_t)i*144 + u];

  // z-part A-frags: sc3 * Wb^T (row = h = l15, k = kg*8+e)
  const float sc1 = 0.14433756729740643f;   // sqrt(1/48)
  const float sc3 = 0.5773502691896258f;    // sqrt(1/3)
  us8 af[4];
  #pragma unroll
  for (int ks = 0; ks < 4; ks++) {
    #pragma unroll
    for (int kc = 0; kc < 8; kc++) {
      af[ks][kc] = (l15 < 12) ? f2bf(sc3 * Wb[(size_t)(ks*32 + kg*8 + kc)*12 + l15])
                              : (unsigned short)0;
    }
  }
  __syncthreads();

  // aug A-frag for this lane's head (row l15), K-slice kg*8..kg*8+7:
  // [sc1*q(16) | hw*qp(12) | -0.5hw | sc3*bb - 0.5hw*|qp|^2 | 0 0]
  float hw = (l15 < 12) ? log1pf(expf(head_w[l15])) * 0.13608276348795434f : 0.f;
  us8 aug;
  #pragma unroll
  for (int e = 0; e < 8; e++) {
    int idx = kg*8 + e;
    float v = 0.f;
    if (l15 < 12) {
      if (idx < 16) v = sc1 * qi[l15*16 + idx];
      else if (idx < 28) v = hw * qpi[l15*12 + (idx-16)];
      else if (idx == 28) v = -0.5f * hw;
      else if (idx == 29) {
        float s2 = 0.f;
        #pragma unroll
        for (int m = 0; m < 12; m++) { float d = qpi[l15*12 + m]; s2 += d*d; }
        v = sc3 * bb[l15] - 0.5f * hw * s2;
      }
    }
    aug[e] = f2bf(v);
  }
  us8 zero8 = {0,0,0,0,0,0,0,0};
  bf16x8 augb = __builtin_bit_cast(bf16x8, aug);
  bf16x8 zerob = __builtin_bit_cast(bf16x8, zero8);

  int jcol = jt*64 + w*16 + l15;
  const float* zr = z + ((size_t)i*NN + jcol)*CZ;
  f32x4 acc = {0.f, 0.f, 0.f, 0.f};
  #pragma unroll
  for (int ks = 0; ks < 4; ks++) {
    float4 z0 = *(const float4*)(zr + ks*32 + kg*8);
    float4 z1 = *(const float4*)(zr + ks*32 + kg*8 + 4);
    us8 bv;
    bv[0] = f2bf(z0.x); bv[1] = f2bf(z0.y); bv[2] = f2bf(z0.z); bv[3] = f2bf(z0.w);
    bv[4] = f2bf(z1.x); bv[5] = f2bf(z1.y); bv[6] = f2bf(z1.z); bv[7] = f2bf(z1.w);
    acc = __builtin_amdgcn_mfma_f32_16x16x32_bf16(
        __builtin_bit_cast(bf16x8, af[ks]), __builtin_bit_cast(bf16x8, bv), acc, 0, 0, 0);
  }

  int jtile = jt*4 + w;
  const us8* Bq8 = (const us8*)Bq;
  #pragma unroll
  for (int hp = 0; hp < 12; hp++) {
    us8 bqv = Bq8[(size_t)(jtile*12 + hp)*64 + kg*16 + l15];
    acc = __builtin_amdgcn_mfma_f32_16x16x32_bf16(
        (l15 == hp) ? augb : zerob, __builtin_bit_cast(bf16x8, bqv), acc, 0, 0, 0);
  }

  if (kg < 3) {
    #pragma unroll
    for (int r = 0; r < 4; r++) {
      int h = kg*4 + r;
      a[((size_t)i*12 + h)*768 + jcol] = acc[r];
    }
  }
}

// ---------------------------------------------------------------------------
// K3: softmax over j for each (i,h) row; reads fp32 logits, writes bf16 probs
__global__ void k_softmax(const float* __restrict__ a, unsigned short* __restrict__ p_bf) {
  size_t row = blockIdx.x;
  const float* p = a + row*NN;
  int t = threadIdx.x;
  float v0 = p[t], v1 = p[t+256], v2 = p[t+512];
  float m = fmaxf(fmaxf(v0, v1), v2);
  __shared__ float red[4];
  for (int off = 32; off; off >>= 1) m = fmaxf(m, __shfl_xor(m, off));
  int wid = t >> 6, lane = t & 63;
  if (lane == 0) red[wid] = m;
  __syncthreads();
  if (t == 0) {
    float mm = red[0];
    for (int w = 1; w < 4; w++) mm = fmaxf(mm, red[w]);
    red[0] = mm;
  }
  __syncthreads();
  m = red[0];
  float e0 = expf(v0 - m), e1 = expf(v1 - m), e2 = expf(v2 - m);
  float ssum = e0 + e1 + e2;
  for (int off = 32; off; off >>= 1) ssum += __shfl_xor(ssum, off);
  __shared__ float red2[4];
  if (lane == 0) red2[wid] = ssum;
  __syncthreads();
  if (t == 0) {
    float ss = 0.f;
    for (int w = 0; w < 4; w++) ss += red2[w];
    red2[0] = ss;
  }
  __syncthreads();
  float inv = 1.0f / red2[0];
  unsigned short* o = p_bf + row*NN;
  o[t]     = f2bf(e0*inv);
  o[t+256] = f2bf(e1*inv);
  o[t+512] = f2bf(e2*inv);
}

// ---------------------------------------------------------------------------
// K4: o = p@v ; o_pt = p@v_pts then inverse frame + norm. grid 768 x 320
__global__ void k_ov(const unsigned short* __restrict__ p_bf, const float* __restrict__ vv,
                     const float* __restrict__ kvpts, const float* __restrict__ rot,
                     const float* __restrict__ trans, float* __restrict__ cat) {
  __shared__ float al[12][65];
  __shared__ float R[9];
  __shared__ float T[3];
  int i = blockIdx.x, t = threadIdx.x;
  if (t < 9) R[t] = rot[(size_t)i*9 + t];
  if (t < 3) T[t] = trans[(size_t)i*3 + t];
  float acc0 = 0.f, acc1 = 0.f, acc2 = 0.f;
  for (int jt = 0; jt < 12; jt++) {
    __syncthreads();
    for (int idx = t; idx < 768; idx += 320) {
      int h = idx >> 6, jj = idx & 63;
      al[h][jj] = bf2f(p_bf[((size_t)i*12 + h)*768 + jt*64 + jj]);
    }
    __syncthreads();
    int j0 = jt * 64;
    if (t < 192) {
      int h = t >> 4;
      for (int jj = 0; jj < 64; jj++)
        acc0 += al[h][jj] * vv[(size_t)(j0+jj)*192 + t];
    } else if (t < 288) {
      int m = t - 192, h = m >> 3, pp = m & 7;
      for (int jj = 0; jj < 64; jj++) {
        float wgt = al[h][jj];
        const float* vp = kvpts + ((size_t)(j0+jj)*144 + h*12 + 4 + pp)*3;
        acc0 += wgt * vp[0]; acc1 += wgt * vp[1]; acc2 += wgt * vp[2];
      }
    }
  }
  if (t < 192) {
    cat[(size_t)i*CATC + t] = acc0;
  } else if (t < 288) {
    int m = t - 192;
    float x0 = acc0 - T[0], x1 = acc1 - T[1], x2 = acc2 - T[2];
    float ox = R[0]*x0 + R[3]*x1 + R[6]*x2;
    float oy = R[1]*x0 + R[4]*x1 + R[7]*x2;
    float oz = R[2]*x0 + R[5]*x1 + R[8]*x2;
    float nrm = sqrtf(ox*ox + oy*oy + oz*oz + 1e-8f);
    float* c = cat + (size_t)i*CATC;
    c[192 + m] = ox; c[288 + m] = oy; c[384 + m] = oz; c[480 + m] = nrm;
  }
}

// ---------------------------------------------------------------------------
// K5 (MFMA): o_pair[i][h][c] = sum_j p[h][j] z[i][j][c].
__global__ void k_opair(const unsigned short* __restrict__ p_bf,
                        const float* __restrict__ z, float* __restrict__ cat) {
  int i = blockIdx.x, t = threadIdx.x;
  int w = t >> 6, l = t & 63, kg = l >> 4, l15 = l & 15;
  int cb = w * 32;
  f32x4 acc0 = {0.f,0.f,0.f,0.f}, acc1 = {0.f,0.f,0.f,0.f};
  const unsigned short* prow = p_bf + ((size_t)i*12 + l15)*768 + kg*8;
  const float* zb = z + (size_t)i*NN*CZ;
  for (int ks = 0; ks < 24; ks++) {
    int j0 = ks * 32;
    us8 av;
    if (l15 < 12) {
      av = *(const us8*)(prow + j0);
    } else {
      av = (us8){0,0,0,0,0,0,0,0};
    }
    const float* zq = zb + (size_t)(j0 + kg*8)*CZ + cb + l15;
    us8 b0, b1;
    #pragma unroll
    for (int kc = 0; kc < 8; kc++) {
      b0[kc] = f2bf(zq[(size_t)kc*CZ]);
      b1[kc] = f2bf(zq[(size_t)kc*CZ + 16]);
    }
    acc0 = __builtin_amdgcn_mfma_f32_16x16x32_bf16(
        __builtin_bit_cast(bf16x8, av), __builtin_bit_cast(bf16x8, b0), acc0, 0, 0, 0);
    acc1 = __builtin_amdgcn_mfma_f32_16x16x32_bf16(
        __builtin_bit_cast(bf16x8, av), __builtin_bit_cast(bf16x8, b1), acc1, 0, 0, 0);
  }
  #pragma unroll
  for (int r = 0; r < 4; r++) {
    int h = kg*4 + r;
    if (h < 12) {
      float* cc = cat + (size_t)i*CATC + 576 + (size_t)h*128;
      cc[cb + l15]      = acc0[r];
      cc[cb + 16 + l15] = acc1[r];
    }
  }
}

// ---------------------------------------------------------------------------
// K6: out = cat @ Wout + bout. ROWS=3/block -> grid 256, x8-unrolled loads.
#define OROWS 3
__global__ void k_out(const float* __restrict__ cat, const float* __restrict__ Wout,
                      const float* __restrict__ bout, float* __restrict__ out) {
  __shared__ float cl[OROWS*CATC];
  int i0 = blockIdx.x*OROWS, t = threadIdx.x;
  for (int idx = t; idx < OROWS*CATC; idx += 384) cl[idx] = cat[(size_t)i0*CATC + idx];
  __syncthreads();
  float acc[OROWS];
  #pragma unroll
  for (int g = 0; g < OROWS; g++) acc[g] = 0.f;
  for (int r = 0; r < CATC; r += 8) {
    float wv[8];
    #pragma unroll
    for (int u = 0; u < 8; u++) wv[u] = Wout[(size_t)(r+u)*384 + t];
    #pragma unroll
    for (int u = 0; u < 8; u++) {
      #pragma unroll
      for (int g = 0; g < OROWS; g++) acc[g] += cl[g*CATC + r + u] * wv[u];
    }
  }
  float bo = bout[t];
  #pragma unroll
  for (int g = 0; g < OROWS; g++) out[(size_t)(i0+g)*384 + t] = acc[g] + bo;
}

// ---------------------------------------------------------------------------
extern "C" void kernel_launch(void* const* d_in, const int* in_sizes, int n_in,
                              void* d_out, int out_size, void* d_ws, size_t ws_size,
                              hipStream_t stream) {
  const float* s      = (const float*)d_in[0];
  const float* z      = (const float*)d_in[1];
  const float* rot    = (const float*)d_in[2];
  const float* trans  = (const float*)d_in[3];
  const float* Wq     = (const float*)d_in[4];
  const float* bq     = (const float*)d_in[5];
  const float* Wkv    = (const float*)d_in[6];
  const float* bkv    = (const float*)d_in[7];
  const float* Wqp    = (const float*)d_in[8];
  const float* bqp    = (const float*)d_in[9];
  const float* Wkvp   = (const float*)d_in[10];
  const float* bkvp   = (const float*)d_in[11];
  const float* Wb     = (const float*)d_in[12];
  const float* bb     = (const float*)d_in[13];
  const float* head_w = (const float*)d_in[14];
  const float* Wout   = (const float*)d_in[15];
  const float* bout   = (const float*)d_in[16];
  float* out = (float*)d_out;

  float* ws    = (float*)d_ws;
  float* q     = ws;                    // 147456
  float* kk    = q     + 147456;        // 147456
  float* vv    = kk    + 147456;        // 147456
  float* qpts  = vv    + 147456;        // 110592
  float* kvpts = qpts  + 110592;        // 331776
  float* a     = kvpts + 331776;        // 7077888  [i][h][j] fp32 logits
  unsigned short* p_bf = (unsigned short*)(a + 7077888);  // 7077888 bf16 probs
  float* cat   = (float*)(p_bf + 7077888);                // 1622016
  unsigned short* Bq = (unsigned short*)(cat + 1622016);  // 294912 bf16

  k_proj<<<768, 256, 0, stream>>>(s, rot, trans, Wq, bq, Wkv, bkv, Wqp, bqp,
                                  Wkvp, bkvp, q, kk, vv, qpts, kvpts);
  k_prep<<<48, 256, 0, stream>>>(kk, kvpts, Bq);
  k_logits<<<dim3(12, 768), 256, 0, stream>>>(q, qpts, z, Wb, bb, head_w, Bq, a);
  k_softmax<<<9216, 256, 0, stream>>>(a, p_bf);
  k_ov<<<768, 320, 0, stream>>>(p_bf, vv, kvpts, rot, trans, cat);
  k_opair<<<768, 256, 0, stream>>>(p_bf, z, cat);
  k_out<<<256, 384, 0, stream>>>(cat, Wout, bout, out);
}

// Round 6
// 402.838 us; speedup vs baseline: 1.9296x; 1.3078x over previous
//
#include <hip/hip_runtime.h>
#include <hip/hip_bf16.h>
#include <cmath>

// Problem constants
#define NN 768
#define CS 384
#define CZ 128
#define CH 16
#define HH 12
#define PQ 4
#define PV 8
#define CATC 2112           // H*(CZ+CH+PV*4)

typedef __attribute__((ext_vector_type(8))) __bf16 bf16x8;
typedef __attribute__((ext_vector_type(8))) unsigned short us8;
typedef __attribute__((ext_vector_type(4))) float f32x4;

__device__ __forceinline__ unsigned short f2bf(float f) {
  unsigned int u = __builtin_bit_cast(unsigned int, f);
  u += 0x7FFFu + ((u >> 16) & 1u);   // RNE
  return (unsigned short)(u >> 16);
}
__device__ __forceinline__ float bf2f(unsigned short u) {
  return __builtin_bit_cast(float, ((unsigned int)u) << 16);
}

// ---------------------------------------------------------------------------
// K1: projections q,k,v,q_pts,kv_pts (with frame application)
// grid 768 blocks x 256 threads
__global__ void k_proj(const float* __restrict__ s, const float* __restrict__ rot,
                       const float* __restrict__ trans,
                       const float* __restrict__ Wq, const float* __restrict__ bq,
                       const float* __restrict__ Wkv, const float* __restrict__ bkv,
                       const float* __restrict__ Wqp, const float* __restrict__ bqp,
                       const float* __restrict__ Wkvp, const float* __restrict__ bkvp,
                       float* __restrict__ q, float* __restrict__ kk, float* __restrict__ vv,
                       float* __restrict__ qpts, float* __restrict__ kvpts) {
  __shared__ float srow[CS];
  __shared__ float rawq[144];
  __shared__ float rawkv[432];
  __shared__ float R[9];
  __shared__ float T[3];
  int n = blockIdx.x, t = threadIdx.x;
  for (int u = t; u < CS; u += 256) srow[u] = s[(size_t)n*CS + u];
  if (t < 9) R[t] = rot[(size_t)n*9 + t];
  if (t < 3) T[t] = trans[(size_t)n*3 + t];
  __syncthreads();

  for (int col = t; col < 192; col += 256) {
    float acc = bq[col];
    for (int c = 0; c < CS; c++) acc += srow[c] * Wq[(size_t)c*192 + col];
    q[(size_t)n*192 + col] = acc;
  }
  for (int col = t; col < 384; col += 256) {
    float acc = bkv[col];
    for (int c = 0; c < CS; c++) acc += srow[c] * Wkv[(size_t)c*384 + col];
    int h = col >> 5, u2 = col & 31;
    if (u2 < 16) kk[(size_t)n*192 + h*16 + u2] = acc;
    else         vv[(size_t)n*192 + h*16 + (u2-16)] = acc;
  }
  for (int col = t; col < 144; col += 256) {
    float acc = bqp[col];
    for (int c = 0; c < CS; c++) acc += srow[c] * Wqp[(size_t)c*144 + col];
    rawq[col] = acc;
  }
  for (int col = t; col < 432; col += 256) {
    float acc = bkvp[col];
    for (int c = 0; c < CS; c++) acc += srow[c] * Wkvp[(size_t)c*432 + col];
    rawkv[col] = acc;
  }
  __syncthreads();

  for (int u = t; u < 48*3; u += 256) {
    int m = u / 3, x = u % 3;
    float p0 = rawq[0*48 + m], p1 = rawq[1*48 + m], p2 = rawq[2*48 + m];
    qpts[((size_t)n*48 + m)*3 + x] = R[x*3+0]*p0 + R[x*3+1]*p1 + R[x*3+2]*p2 + T[x];
  }
  for (int u = t; u < 144*3; u += 256) {
    int m = u / 3, x = u % 3;
    float p0 = rawkv[0*144 + m], p1 = rawkv[1*144 + m], p2 = rawkv[2*144 + m];
    kvpts[((size_t)n*144 + m)*3 + x] = R[x*3+0]*p0 + R[x*3+1]*p1 + R[x*3+2]*p2 + T[x];
  }
}

// ---------------------------------------------------------------------------
// K_prep: augmented B matrix for logits (see R4 notes). grid 48 x 256
__global__ void k_prep(const float* __restrict__ kk, const float* __restrict__ kvpts,
                       unsigned short* __restrict__ Bq) {
  int jt16 = blockIdx.x, t = threadIdx.x;
  for (int u = t; u < 768; u += 256) {
    int hp = u >> 6, kg = (u >> 4) & 3, l15 = u & 15;
    int j = jt16*16 + l15;
    unsigned short vals[8];
    #pragma unroll
    for (int e = 0; e < 8; e++) {
      int cc = kg*8 + e;
      float v;
      if (cc < 16) {
        v = kk[(size_t)j*192 + hp*16 + cc];
      } else if (cc < 28) {
        v = kvpts[(size_t)j*432 + hp*36 + (cc-16)];
      } else if (cc == 28) {
        float s2 = 0.f;
        #pragma unroll
        for (int m = 0; m < 12; m++) {
          float d = kvpts[(size_t)j*432 + hp*36 + m];
          s2 += d*d;
        }
        v = s2;
      } else if (cc == 29) {
        v = 1.0f;
      } else {
        v = 0.f;
      }
      vals[e] = f2bf(v);
    }
    *(us8*)(Bq + ((size_t)(jt16*12 + hp)*64 + kg*16 + l15)*8) = *(const us8*)vals;
  }
}

// ---------------------------------------------------------------------------
// K_prep_v: swizzled bf16 B-matrix for k_ov's per-head GEMM.
// Vq8[(((h*3+nt)*24+ks)<<6) | (kg<<4) | l15], elem e -> V_h[j][col]
//   j = ks*32+kg*8+e, col = nt*16+l15:
//   col<16 -> vv[j][h*16+col]; col in [16,40) -> v_pts comp; else 0.
// grid 432 x 256 (one us8 per thread)
__global__ void k_prep_v(const float* __restrict__ vv, const float* __restrict__ kvpts,
                         unsigned short* __restrict__ Vq) {
  int g = blockIdx.x*256 + threadIdx.x;   // < 110592
  int l15 = g & 15;
  int kg  = (g >> 4) & 3;
  int r2  = g >> 6;          // ((h*3+nt)*24 + ks)
  int ks  = r2 % 24;
  int hn  = r2 / 24;
  int nt  = hn % 3;
  int h   = hn / 3;
  int col = nt*16 + l15;
  unsigned short vals[8];
  #pragma unroll
  for (int e = 0; e < 8; e++) {
    int j = ks*32 + kg*8 + e;
    float v = 0.f;
    if (col < 16)      v = vv[(size_t)j*192 + h*16 + col];
    else if (col < 40) v = kvpts[(size_t)j*432 + h*36 + 12 + (col-16)];
    vals[e] = f2bf(v);
  }
  *(us8*)(Vq + (size_t)g*8) = *(const us8*)vals;
}

// ---------------------------------------------------------------------------
// K2 (pure MFMA): a[i][h][j] = [sc3*Wb^T | augA] x [z^T | augB].
// grid 768 (one block per i) x 256; setup ONCE, then 12 j-tiles streamed.
__global__ void k_logits(const float* __restrict__ q, const float* __restrict__ qpts,
                         const float* __restrict__ z, const float* __restrict__ Wb,
                         const float* __restrict__ bb, const float* __restrict__ head_w,
                         const unsigned short* __restrict__ Bq, float* __restrict__ a) {
  __shared__ float qi[192];
  __shared__ float qpi[144];
  int i = blockIdx.x, t = threadIdx.x;
  int w = t >> 6, l = t & 63, kg = l >> 4, l15 = l & 15;
  for (int u = t; u < 192; u += 256) qi[u] = q[(size_t)i*192 + u];
  for (int u = t; u < 144; u += 256) qpi[u] = qpts[(size_t)i*144 + u];

  const float sc1 = 0.14433756729740643f;   // sqrt(1/48)
  const float sc3 = 0.5773502691896258f;    // sqrt(1/3)
  us8 af[4];
  #pragma unroll
  for (int ks = 0; ks < 4; ks++) {
    #pragma unroll
    for (int kc = 0; kc < 8; kc++) {
      af[ks][kc] = (l15 < 12) ? f2bf(sc3 * Wb[(size_t)(ks*32 + kg*8 + kc)*12 + l15])
                              : (unsigned short)0;
    }
  }
  __syncthreads();

  // aug A-frag: [sc1*q(16) | hw*qp(12) | -0.5hw | sc3*bb-0.5hw*|qp|^2 | 0 0]
  float hw = (l15 < 12) ? log1pf(expf(head_w[l15])) * 0.13608276348795434f : 0.f;
  us8 aug;
  #pragma unroll
  for (int e = 0; e < 8; e++) {
    int idx = kg*8 + e;
    float v = 0.f;
    if (l15 < 12) {
      if (idx < 16) v = sc1 * qi[l15*16 + idx];
      else if (idx < 28) v = hw * qpi[l15*12 + (idx-16)];
      else if (idx == 28) v = -0.5f * hw;
      else if (idx == 29) {
        float s2 = 0.f;
        #pragma unroll
        for (int m = 0; m < 12; m++) { float d = qpi[l15*12 + m]; s2 += d*d; }
        v = sc3 * bb[l15] - 0.5f * hw * s2;
      }
    }
    aug[e] = f2bf(v);
  }
  us8 zero8 = {0,0,0,0,0,0,0,0};
  bf16x8 augb = __builtin_bit_cast(bf16x8, aug);
  bf16x8 zerob = __builtin_bit_cast(bf16x8, zero8);
  const us8* Bq8 = (const us8*)Bq;

  for (int jt = 0; jt < 12; jt++) {
    int jcol = jt*64 + w*16 + l15;
    const float* zr = z + ((size_t)i*NN + jcol)*CZ;
    f32x4 acc = {0.f, 0.f, 0.f, 0.f};
    #pragma unroll
    for (int ks = 0; ks < 4; ks++) {
      float4 z0 = *(const float4*)(zr + ks*32 + kg*8);
      float4 z1 = *(const float4*)(zr + ks*32 + kg*8 + 4);
      us8 bv;
      bv[0] = f2bf(z0.x); bv[1] = f2bf(z0.y); bv[2] = f2bf(z0.z); bv[3] = f2bf(z0.w);
      bv[4] = f2bf(z1.x); bv[5] = f2bf(z1.y); bv[6] = f2bf(z1.z); bv[7] = f2bf(z1.w);
      acc = __builtin_amdgcn_mfma_f32_16x16x32_bf16(
          __builtin_bit_cast(bf16x8, af[ks]), __builtin_bit_cast(bf16x8, bv), acc, 0, 0, 0);
    }
    int jtile = jt*4 + w;
    #pragma unroll
    for (int hp = 0; hp < 12; hp++) {
      us8 bqv = Bq8[(size_t)(jtile*12 + hp)*64 + kg*16 + l15];
      acc = __builtin_amdgcn_mfma_f32_16x16x32_bf16(
          (l15 == hp) ? augb : zerob, __builtin_bit_cast(bf16x8, bqv), acc, 0, 0, 0);
    }
    if (kg < 3) {
      #pragma unroll
      for (int r = 0; r < 4; r++) {
        int h = kg*4 + r;
        a[((size_t)i*12 + h)*768 + jcol] = acc[r];
      }
    }
  }
}

// ---------------------------------------------------------------------------
// K3: softmax over j for each (i,h) row; reads fp32 logits, writes bf16 probs
__global__ void k_softmax(const float* __restrict__ a, unsigned short* __restrict__ p_bf) {
  size_t row = blockIdx.x;
  const float* p = a + row*NN;
  int t = threadIdx.x;
  float v0 = p[t], v1 = p[t+256], v2 = p[t+512];
  float m = fmaxf(fmaxf(v0, v1), v2);
  __shared__ float red[4];
  for (int off = 32; off; off >>= 1) m = fmaxf(m, __shfl_xor(m, off));
  int wid = t >> 6, lane = t & 63;
  if (lane == 0) red[wid] = m;
  __syncthreads();
  if (t == 0) {
    float mm = red[0];
    for (int w = 1; w < 4; w++) mm = fmaxf(mm, red[w]);
    red[0] = mm;
  }
  __syncthreads();
  m = red[0];
  float e0 = expf(v0 - m), e1 = expf(v1 - m), e2 = expf(v2 - m);
  float ssum = e0 + e1 + e2;
  for (int off = 32; off; off >>= 1) ssum += __shfl_xor(ssum, off);
  __shared__ float red2[4];
  if (lane == 0) red2[wid] = ssum;
  __syncthreads();
  if (t == 0) {
    float ss = 0.f;
    for (int w = 0; w < 4; w++) ss += red2[w];
    red2[0] = ss;
  }
  __syncthreads();
  float inv = 1.0f / red2[0];
  unsigned short* o = p_bf + row*NN;
  o[t]     = f2bf(e0*inv);
  o[t+256] = f2bf(e1*inv);
  o[t+512] = f2bf(e2*inv);
}

// ---------------------------------------------------------------------------
// K4 (MFMA): per-head GEMM P_h[768x768] @ V_h[768x40] -> o (cols 0..15) and
// o_pt raw (cols 16..39), then frame-inverse + norm epilogue via LDS.
// grid (48 i-tiles, 12 h) x 256 (waves 0..2 = N-tiles, wave 3 idle in MFMA).
__global__ void k_ov(const unsigned short* __restrict__ p_bf,
                     const unsigned short* __restrict__ Vq,
                     const float* __restrict__ rot, const float* __restrict__ trans,
                     float* __restrict__ cat) {
  __shared__ float opt[16][28];
  __shared__ float Rl[16][9];
  __shared__ float Tl[16][3];
  int it = blockIdx.x, h = blockIdx.y, t = threadIdx.x;
  int i0 = it*16;
  int w = t >> 6, l = t & 63, kg = l >> 4, l15 = l & 15;
  if (t < 144) Rl[t/9][t%9] = rot[(size_t)(i0 + t/9)*9 + (t%9)];
  if (t >= 192 && t < 240) {
    int u = t - 192;
    Tl[u/3][u%3] = trans[(size_t)(i0 + u/3)*3 + (u%3)];
  }
  f32x4 acc = {0.f,0.f,0.f,0.f};
  if (w < 3) {
    const unsigned short* prow = p_bf + ((size_t)(i0 + l15)*12 + h)*768 + kg*8;
    const us8* vq = (const us8*)Vq + (size_t)(h*3 + w)*24*64 + kg*16 + l15;
    for (int ks = 0; ks < 24; ks++) {
      us8 av = *(const us8*)(prow + ks*32);
      us8 bv = vq[(size_t)ks*64];
      acc = __builtin_amdgcn_mfma_f32_16x16x32_bf16(
          __builtin_bit_cast(bf16x8, av), __builtin_bit_cast(bf16x8, bv), acc, 0, 0, 0);
    }
  }
  if (w == 0) {
    #pragma unroll
    for (int r = 0; r < 4; r++)
      cat[(size_t)(i0 + kg*4 + r)*CATC + h*16 + l15] = acc[r];
  } else if (w == 1) {
    #pragma unroll
    for (int r = 0; r < 4; r++) opt[kg*4 + r][l15] = acc[r];
  } else if (w == 2) {
    if (l15 < 8) {
      #pragma unroll
      for (int r = 0; r < 4; r++) opt[kg*4 + r][16 + l15] = acc[r];
    }
  }
  __syncthreads();
  if (t < 128) {
    int ip = t >> 3, p = t & 7;
    float x0 = opt[ip][p*3+0] - Tl[ip][0];
    float x1 = opt[ip][p*3+1] - Tl[ip][1];
    float x2 = opt[ip][p*3+2] - Tl[ip][2];
    const float* R = Rl[ip];
    float ox = R[0]*x0 + R[3]*x1 + R[6]*x2;
    float oy = R[1]*x0 + R[4]*x1 + R[7]*x2;
    float oz = R[2]*x0 + R[5]*x1 + R[8]*x2;
    float nrm = sqrtf(ox*ox + oy*oy + oz*oz + 1e-8f);
    float* c = cat + (size_t)(i0 + ip)*CATC;
    int m = h*8 + p;
    c[192 + m] = ox; c[288 + m] = oy; c[384 + m] = oz; c[480 + m] = nrm;
  }
}

// ---------------------------------------------------------------------------
// K5 (MFMA): o_pair[i][h][c] = sum_j p[h][j] z[i][j][c].
__global__ void k_opair(const unsigned short* __restrict__ p_bf,
                        const float* __restrict__ z, float* __restrict__ cat) {
  int i = blockIdx.x, t = threadIdx.x;
  int w = t >> 6, l = t & 63, kg = l >> 4, l15 = l & 15;
  int cb = w * 32;
  f32x4 acc0 = {0.f,0.f,0.f,0.f}, acc1 = {0.f,0.f,0.f,0.f};
  const unsigned short* prow = p_bf + ((size_t)i*12 + l15)*768 + kg*8;
  const float* zb = z + (size_t)i*NN*CZ;
  for (int ks = 0; ks < 24; ks++) {
    int j0 = ks * 32;
    us8 av;
    if (l15 < 12) {
      av = *(const us8*)(prow + j0);
    } else {
      av = (us8){0,0,0,0,0,0,0,0};
    }
    const float* zq = zb + (size_t)(j0 + kg*8)*CZ + cb + l15;
    us8 b0, b1;
    #pragma unroll
    for (int kc = 0; kc < 8; kc++) {
      b0[kc] = f2bf(zq[(size_t)kc*CZ]);
      b1[kc] = f2bf(zq[(size_t)kc*CZ + 16]);
    }
    acc0 = __builtin_amdgcn_mfma_f32_16x16x32_bf16(
        __builtin_bit_cast(bf16x8, av), __builtin_bit_cast(bf16x8, b0), acc0, 0, 0, 0);
    acc1 = __builtin_amdgcn_mfma_f32_16x16x32_bf16(
        __builtin_bit_cast(bf16x8, av), __builtin_bit_cast(bf16x8, b1), acc1, 0, 0, 0);
  }
  #pragma unroll
  for (int r = 0; r < 4; r++) {
    int h = kg*4 + r;
    if (h < 12) {
      float* cc = cat + (size_t)i*CATC + 576 + (size_t)h*128;
      cc[cb + l15]      = acc0[r];
      cc[cb + 16 + l15] = acc1[r];
    }
  }
}

// ---------------------------------------------------------------------------
// K6: out = cat @ Wout + bout. ROWS=3/block -> grid 256, x8-unrolled loads.
#define OROWS 3
__global__ void k_out(const float* __restrict__ cat, const float* __restrict__ Wout,
                      const float* __restrict__ bout, float* __restrict__ out) {
  __shared__ float cl[OROWS*CATC];
  int i0 = blockIdx.x*OROWS, t = threadIdx.x;
  for (int idx = t; idx < OROWS*CATC; idx += 384) cl[idx] = cat[(size_t)i0*CATC + idx];
  __syncthreads();
  float acc[OROWS];
  #pragma unroll
  for (int g = 0; g < OROWS; g++) acc[g] = 0.f;
  for (int r = 0; r < CATC; r += 8) {
    float wv[8];
    #pragma unroll
    for (int u = 0; u < 8; u++) wv[u] = Wout[(size_t)(r+u)*384 + t];
    #pragma unroll
    for (int u = 0; u < 8; u++) {
      #pragma unroll
      for (int g = 0; g < OROWS; g++) acc[g] += cl[g*CATC + r + u] * wv[u];
    }
  }
  float bo = bout[t];
  #pragma unroll
  for (int g = 0; g < OROWS; g++) out[(size_t)(i0+g)*384 + t] = acc[g] + bo;
}

// ---------------------------------------------------------------------------
extern "C" void kernel_launch(void* const* d_in, const int* in_sizes, int n_in,
                              void* d_out, int out_size, void* d_ws, size_t ws_size,
                              hipStream_t stream) {
  const float* s      = (const float*)d_in[0];
  const float* z      = (const float*)d_in[1];
  const float* rot    = (const float*)d_in[2];
  const float* trans  = (const float*)d_in[3];
  const float* Wq     = (const float*)d_in[4];
  const float* bq     = (const float*)d_in[5];
  const float* Wkv    = (const float*)d_in[6];
  const float* bkv    = (const float*)d_in[7];
  const float* Wqp    = (const float*)d_in[8];
  const float* bqp    = (const float*)d_in[9];
  const float* Wkvp   = (const float*)d_in[10];
  const float* bkvp   = (const float*)d_in[11];
  const float* Wb     = (const float*)d_in[12];
  const float* bb     = (const float*)d_in[13];
  const float* head_w = (const float*)d_in[14];
  const float* Wout   = (const float*)d_in[15];
  const float* bout   = (const float*)d_in[16];
  float* out = (float*)d_out;

  float* ws    = (float*)d_ws;
  float* q     = ws;                    // 147456
  float* kk    = q     + 147456;        // 147456
  float* vv    = kk    + 147456;        // 147456
  float* qpts  = vv    + 147456;        // 110592
  float* kvpts = qpts  + 110592;        // 331776
  float* a     = kvpts + 331776;        // 7077888  [i][h][j] fp32 logits
  unsigned short* p_bf = (unsigned short*)(a + 7077888);  // 7077888 bf16 probs
  float* cat   = (float*)(p_bf + 7077888);                // 1622016
  unsigned short* Bq = (unsigned short*)(cat + 1622016);  // 294912 bf16
  unsigned short* Vq = Bq + 294912;                       // 884736 bf16

  k_proj<<<768, 256, 0, stream>>>(s, rot, trans, Wq, bq, Wkv, bkv, Wqp, bqp,
                                  Wkvp, bkvp, q, kk, vv, qpts, kvpts);
  k_prep<<<48, 256, 0, stream>>>(kk, kvpts, Bq);
  k_prep_v<<<432, 256, 0, stream>>>(vv, kvpts, Vq);
  k_logits<<<768, 256, 0, stream>>>(q, qpts, z, Wb, bb, head_w, Bq, a);
  k_softmax<<<9216, 256, 0, stream>>>(a, p_bf);
  k_ov<<<dim3(48, 12), 256, 0, stream>>>(p_bf, Vq, rot, trans, cat);
  k_opair<<<768, 256, 0, stream>>>(p_bf, z, cat);
  k_out<<<256, 384, 0, stream>>>(cat, Wout, bout, out);
}

// Round 7
// 391.127 us; speedup vs baseline: 1.9873x; 1.0299x over previous
//
#include <hip/hip_runtime.h>
#include <hip/hip_bf16.h>
#include <cmath>

// Problem constants
#define NN 768
#define CS 384
#define CZ 128
#define CH 16
#define HH 12
#define PQ 4
#define PV 8
#define CATC 2112           // H*(CZ+CH+PV*4)

typedef __attribute__((ext_vector_type(8))) __bf16 bf16x8;
typedef __attribute__((ext_vector_type(8))) unsigned short us8;
typedef __attribute__((ext_vector_type(4))) float f32x4;

__device__ __forceinline__ unsigned short f2bf(float f) {
  unsigned int u = __builtin_bit_cast(unsigned int, f);
  u += 0x7FFFu + ((u >> 16) & 1u);   // RNE
  return (unsigned short)(u >> 16);
}
__device__ __forceinline__ float bf2f(unsigned short u) {
  return __builtin_bit_cast(float, ((unsigned int)u) << 16);
}

// ---------------------------------------------------------------------------
// K1: projections q,k,v,q_pts,kv_pts (with frame application)
// grid 768 blocks x 256 threads
__global__ void k_proj(const float* __restrict__ s, const float* __restrict__ rot,
                       const float* __restrict__ trans,
                       const float* __restrict__ Wq, const float* __restrict__ bq,
                       const float* __restrict__ Wkv, const float* __restrict__ bkv,
                       const float* __restrict__ Wqp, const float* __restrict__ bqp,
                       const float* __restrict__ Wkvp, const float* __restrict__ bkvp,
                       float* __restrict__ q, float* __restrict__ kk, float* __restrict__ vv,
                       float* __restrict__ qpts, float* __restrict__ kvpts) {
  __shared__ float srow[CS];
  __shared__ float rawq[144];
  __shared__ float rawkv[432];
  __shared__ float R[9];
  __shared__ float T[3];
  int n = blockIdx.x, t = threadIdx.x;
  for (int u = t; u < CS; u += 256) srow[u] = s[(size_t)n*CS + u];
  if (t < 9) R[t] = rot[(size_t)n*9 + t];
  if (t < 3) T[t] = trans[(size_t)n*3 + t];
  __syncthreads();

  for (int col = t; col < 192; col += 256) {
    float acc = bq[col];
    for (int c = 0; c < CS; c++) acc += srow[c] * Wq[(size_t)c*192 + col];
    q[(size_t)n*192 + col] = acc;
  }
  for (int col = t; col < 384; col += 256) {
    float acc = bkv[col];
    for (int c = 0; c < CS; c++) acc += srow[c] * Wkv[(size_t)c*384 + col];
    int h = col >> 5, u2 = col & 31;
    if (u2 < 16) kk[(size_t)n*192 + h*16 + u2] = acc;
    else         vv[(size_t)n*192 + h*16 + (u2-16)] = acc;
  }
  for (int col = t; col < 144; col += 256) {
    float acc = bqp[col];
    for (int c = 0; c < CS; c++) acc += srow[c] * Wqp[(size_t)c*144 + col];
    rawq[col] = acc;
  }
  for (int col = t; col < 432; col += 256) {
    float acc = bkvp[col];
    for (int c = 0; c < CS; c++) acc += srow[c] * Wkvp[(size_t)c*432 + col];
    rawkv[col] = acc;
  }
  __syncthreads();

  for (int u = t; u < 48*3; u += 256) {
    int m = u / 3, x = u % 3;
    float p0 = rawq[0*48 + m], p1 = rawq[1*48 + m], p2 = rawq[2*48 + m];
    qpts[((size_t)n*48 + m)*3 + x] = R[x*3+0]*p0 + R[x*3+1]*p1 + R[x*3+2]*p2 + T[x];
  }
  for (int u = t; u < 144*3; u += 256) {
    int m = u / 3, x = u % 3;
    float p0 = rawkv[0*144 + m], p1 = rawkv[1*144 + m], p2 = rawkv[2*144 + m];
    kvpts[((size_t)n*144 + m)*3 + x] = R[x*3+0]*p0 + R[x*3+1]*p1 + R[x*3+2]*p2 + T[x];
  }
}

// ---------------------------------------------------------------------------
// K_prep: augmented B matrix for logits (see R4 notes). grid 48 x 256
__global__ void k_prep(const float* __restrict__ kk, const float* __restrict__ kvpts,
                       unsigned short* __restrict__ Bq) {
  int jt16 = blockIdx.x, t = threadIdx.x;
  for (int u = t; u < 768; u += 256) {
    int hp = u >> 6, kg = (u >> 4) & 3, l15 = u & 15;
    int j = jt16*16 + l15;
    unsigned short vals[8];
    #pragma unroll
    for (int e = 0; e < 8; e++) {
      int cc = kg*8 + e;
      float v;
      if (cc < 16) {
        v = kk[(size_t)j*192 + hp*16 + cc];
      } else if (cc < 28) {
        v = kvpts[(size_t)j*432 + hp*36 + (cc-16)];
      } else if (cc == 28) {
        float s2 = 0.f;
        #pragma unroll
        for (int m = 0; m < 12; m++) {
          float d = kvpts[(size_t)j*432 + hp*36 + m];
          s2 += d*d;
        }
        v = s2;
      } else if (cc == 29) {
        v = 1.0f;
      } else {
        v = 0.f;
      }
      vals[e] = f2bf(v);
    }
    *(us8*)(Bq + ((size_t)(jt16*12 + hp)*64 + kg*16 + l15)*8) = *(const us8*)vals;
  }
}

// ---------------------------------------------------------------------------
// K_prep_v: swizzled bf16 B-matrix for k_ov's per-head GEMM. grid 432 x 256
__global__ void k_prep_v(const float* __restrict__ vv, const float* __restrict__ kvpts,
                         unsigned short* __restrict__ Vq) {
  int g = blockIdx.x*256 + threadIdx.x;   // < 110592
  int l15 = g & 15;
  int kg  = (g >> 4) & 3;
  int r2  = g >> 6;          // ((h*3+nt)*24 + ks)
  int ks  = r2 % 24;
  int hn  = r2 / 24;
  int nt  = hn % 3;
  int h   = hn / 3;
  int col = nt*16 + l15;
  unsigned short vals[8];
  #pragma unroll
  for (int e = 0; e < 8; e++) {
    int j = ks*32 + kg*8 + e;
    float v = 0.f;
    if (col < 16)      v = vv[(size_t)j*192 + h*16 + col];
    else if (col < 40) v = kvpts[(size_t)j*432 + h*36 + 12 + (col-16)];
    vals[e] = f2bf(v);
  }
  *(us8*)(Vq + (size_t)g*8) = *(const us8*)vals;
}

// ---------------------------------------------------------------------------
// K_FUSED: logits (MFMA, z pass 1) -> exact softmax in registers ->
// o_pair (MFMA, z pass 2, L3-warm) + bf16 p dump for k_ov.
// grid 768 (one block per i) x 256.
#define PLD 776   // p_lds row stride in ushorts (= 97 us8); rows 4 banks apart
__global__ void __launch_bounds__(256) k_fused(
    const float* __restrict__ q, const float* __restrict__ qpts,
    const float* __restrict__ z, const float* __restrict__ Wb,
    const float* __restrict__ bb, const float* __restrict__ head_w,
    const unsigned short* __restrict__ Bq,
    unsigned short* __restrict__ p_bf, float* __restrict__ cat) {
  __shared__ float qi[192];
  __shared__ float qpi[144];
  __shared__ unsigned short p_lds[12*PLD];
  __shared__ float redm[4][16];
  __shared__ float reds[4][16];
  int i = blockIdx.x, t = threadIdx.x;
  int w = t >> 6, l = t & 63, kg = l >> 4, l15 = l & 15;
  for (int u = t; u < 192; u += 256) qi[u] = q[(size_t)i*192 + u];
  for (int u = t; u < 144; u += 256) qpi[u] = qpts[(size_t)i*144 + u];

  const float sc1 = 0.14433756729740643f;   // sqrt(1/48)
  const float sc3 = 0.5773502691896258f;    // sqrt(1/3)
  us8 af[4];
  #pragma unroll
  for (int ks = 0; ks < 4; ks++) {
    #pragma unroll
    for (int kc = 0; kc < 8; kc++) {
      af[ks][kc] = (l15 < 12) ? f2bf(sc3 * Wb[(size_t)(ks*32 + kg*8 + kc)*12 + l15])
                              : (unsigned short)0;
    }
  }
  __syncthreads();

  // aug A-frag: [sc1*q(16) | hw*qp(12) | -0.5hw | sc3*bb-0.5hw*|qp|^2 | 0 0]
  float hw = (l15 < 12) ? log1pf(expf(head_w[l15])) * 0.13608276348795434f : 0.f;
  us8 aug;
  #pragma unroll
  for (int e = 0; e < 8; e++) {
    int idx = kg*8 + e;
    float v = 0.f;
    if (l15 < 12) {
      if (idx < 16) v = sc1 * qi[l15*16 + idx];
      else if (idx < 28) v = hw * qpi[l15*12 + (idx-16)];
      else if (idx == 28) v = -0.5f * hw;
      else if (idx == 29) {
        float s2 = 0.f;
        #pragma unroll
        for (int m = 0; m < 12; m++) { float d = qpi[l15*12 + m]; s2 += d*d; }
        v = sc3 * bb[l15] - 0.5f * hw * s2;
      }
    }
    aug[e] = f2bf(v);
  }
  us8 zero8 = {0,0,0,0,0,0,0,0};
  bf16x8 augb = __builtin_bit_cast(bf16x8, aug);
  bf16x8 zerob = __builtin_bit_cast(bf16x8, zero8);
  const us8* Bq8 = (const us8*)Bq;

  // ---- phase 1: logits, all 12 j-tiles, kept in registers
  f32x4 lg[12];
  #pragma unroll
  for (int jt = 0; jt < 12; jt++) {
    int jcol = jt*64 + w*16 + l15;
    const float* zr = z + ((size_t)i*NN + jcol)*CZ;
    f32x4 acc = {0.f, 0.f, 0.f, 0.f};
    #pragma unroll
    for (int ks = 0; ks < 4; ks++) {
      float4 z0 = *(const float4*)(zr + ks*32 + kg*8);
      float4 z1 = *(const float4*)(zr + ks*32 + kg*8 + 4);
      us8 bv;
      bv[0] = f2bf(z0.x); bv[1] = f2bf(z0.y); bv[2] = f2bf(z0.z); bv[3] = f2bf(z0.w);
      bv[4] = f2bf(z1.x); bv[5] = f2bf(z1.y); bv[6] = f2bf(z1.z); bv[7] = f2bf(z1.w);
      acc = __builtin_amdgcn_mfma_f32_16x16x32_bf16(
          __builtin_bit_cast(bf16x8, af[ks]), __builtin_bit_cast(bf16x8, bv), acc, 0, 0, 0);
    }
    int jtile = jt*4 + w;
    #pragma unroll
    for (int hp = 0; hp < 12; hp++) {
      us8 bqv = Bq8[(size_t)(jtile*12 + hp)*64 + kg*16 + l15];
      acc = __builtin_amdgcn_mfma_f32_16x16x32_bf16(
          (l15 == hp) ? augb : zerob, __builtin_bit_cast(bf16x8, bqv), acc, 0, 0, 0);
    }
    lg[jt] = acc;
  }

  // ---- phase 2: exact softmax over j for each h = kg*4+r
  float inv[4];
  {
    float mr[4];
    #pragma unroll
    for (int r = 0; r < 4; r++) {
      float m = lg[0][r];
      #pragma unroll
      for (int jt = 1; jt < 12; jt++) m = fmaxf(m, lg[jt][r]);
      #pragma unroll
      for (int off = 1; off < 16; off <<= 1) m = fmaxf(m, __shfl_xor(m, off));
      mr[r] = m;
    }
    if (l15 == 0) {
      #pragma unroll
      for (int r = 0; r < 4; r++) redm[w][kg*4+r] = mr[r];
    }
    __syncthreads();
    float sr[4];
    #pragma unroll
    for (int r = 0; r < 4; r++) {
      int h = kg*4 + r;
      float m = fmaxf(fmaxf(redm[0][h], redm[1][h]), fmaxf(redm[2][h], redm[3][h]));
      float s = 0.f;
      #pragma unroll
      for (int jt = 0; jt < 12; jt++) {
        float e = expf(lg[jt][r] - m);
        lg[jt][r] = e;
        s += e;
      }
      #pragma unroll
      for (int off = 1; off < 16; off <<= 1) s += __shfl_xor(s, off);
      sr[r] = s;
    }
    if (l15 == 0) {
      #pragma unroll
      for (int r = 0; r < 4; r++) reds[w][kg*4+r] = sr[r];
    }
    __syncthreads();
    #pragma unroll
    for (int r = 0; r < 4; r++) {
      int h = kg*4 + r;
      inv[r] = 1.0f / (reds[0][h] + reds[1][h] + reds[2][h] + reds[3][h]);
    }
  }
  // write bf16 probs to LDS (rows = h, padded stride)
  if (kg < 3) {
    #pragma unroll
    for (int jt = 0; jt < 12; jt++) {
      int jcol = jt*64 + w*16 + l15;
      #pragma unroll
      for (int r = 0; r < 4; r++)
        p_lds[(kg*4+r)*PLD + jcol] = f2bf(lg[jt][r] * inv[r]);
    }
  }
  __syncthreads();

  // coalesced dump of p to global for k_ov
  {
    const us8* pl8 = (const us8*)p_lds;
    us8* pg8 = (us8*)(p_bf + (size_t)i*12*768);
    for (int idx = t; idx < 1152; idx += 256) {
      int h = idx / 96, c8 = idx % 96;
      pg8[h*96 + c8] = pl8[h*97 + c8];
    }
  }

  // ---- phase 3: o_pair = p @ z (z pass 2, L3-warm), A-frags from LDS
  {
    int cb = w * 32;
    f32x4 acc0 = {0.f,0.f,0.f,0.f}, acc1 = {0.f,0.f,0.f,0.f};
    const us8* pl8 = (const us8*)p_lds;
    const float* zb = z + (size_t)i*NN*CZ;
    for (int ks = 0; ks < 24; ks++) {
      us8 av = zero8;
      if (l15 < 12) av = pl8[l15*97 + ks*4 + kg];
      const float* zq = zb + (size_t)(ks*32 + kg*8)*CZ + cb + l15;
      us8 b0, b1;
      #pragma unroll
      for (int kc = 0; kc < 8; kc++) {
        b0[kc] = f2bf(zq[(size_t)kc*CZ]);
        b1[kc] = f2bf(zq[(size_t)kc*CZ + 16]);
      }
      acc0 = __builtin_amdgcn_mfma_f32_16x16x32_bf16(
          __builtin_bit_cast(bf16x8, av), __builtin_bit_cast(bf16x8, b0), acc0, 0, 0, 0);
      acc1 = __builtin_amdgcn_mfma_f32_16x16x32_bf16(
          __builtin_bit_cast(bf16x8, av), __builtin_bit_cast(bf16x8, b1), acc1, 0, 0, 0);
    }
    #pragma unroll
    for (int r = 0; r < 4; r++) {
      int h = kg*4 + r;
      if (h < 12) {
        float* cc = cat + (size_t)i*CATC + 576 + (size_t)h*128;
        cc[cb + l15]      = acc0[r];
        cc[cb + 16 + l15] = acc1[r];
      }
    }
  }
}

// ---------------------------------------------------------------------------
// K4 (MFMA): per-head GEMM P_h[768x768] @ V_h[768x40] -> o and o_pt(+norm).
// grid (48 i-tiles, 12 h) x 256.
__global__ void k_ov(const unsigned short* __restrict__ p_bf,
                     const unsigned short* __restrict__ Vq,
                     const float* __restrict__ rot, const float* __restrict__ trans,
                     float* __restrict__ cat) {
  __shared__ float opt[16][28];
  __shared__ float Rl[16][9];
  __shared__ float Tl[16][3];
  int it = blockIdx.x, h = blockIdx.y, t = threadIdx.x;
  int i0 = it*16;
  int w = t >> 6, l = t & 63, kg = l >> 4, l15 = l & 15;
  if (t < 144) Rl[t/9][t%9] = rot[(size_t)(i0 + t/9)*9 + (t%9)];
  if (t >= 192 && t < 240) {
    int u = t - 192;
    Tl[u/3][u%3] = trans[(size_t)(i0 + u/3)*3 + (u%3)];
  }
  f32x4 acc = {0.f,0.f,0.f,0.f};
  if (w < 3) {
    const unsigned short* prow = p_bf + ((size_t)(i0 + l15)*12 + h)*768 + kg*8;
    const us8* vq = (const us8*)Vq + (size_t)(h*3 + w)*24*64 + kg*16 + l15;
    for (int ks = 0; ks < 24; ks++) {
      us8 av = *(const us8*)(prow + ks*32);
      us8 bv = vq[(size_t)ks*64];
      acc = __builtin_amdgcn_mfma_f32_16x16x32_bf16(
          __builtin_bit_cast(bf16x8, av), __builtin_bit_cast(bf16x8, bv), acc, 0, 0, 0);
    }
  }
  if (w == 0) {
    #pragma unroll
    for (int r = 0; r < 4; r++)
      cat[(size_t)(i0 + kg*4 + r)*CATC + h*16 + l15] = acc[r];
  } else if (w == 1) {
    #pragma unroll
    for (int r = 0; r < 4; r++) opt[kg*4 + r][l15] = acc[r];
  } else if (w == 2) {
    if (l15 < 8) {
      #pragma unroll
      for (int r = 0; r < 4; r++) opt[kg*4 + r][16 + l15] = acc[r];
    }
  }
  __syncthreads();
  if (t < 128) {
    int ip = t >> 3, p = t & 7;
    float x0 = opt[ip][p*3+0] - Tl[ip][0];
    float x1 = opt[ip][p*3+1] - Tl[ip][1];
    float x2 = opt[ip][p*3+2] - Tl[ip][2];
    const float* R = Rl[ip];
    float ox = R[0]*x0 + R[3]*x1 + R[6]*x2;
    float oy = R[1]*x0 + R[4]*x1 + R[7]*x2;
    float oz = R[2]*x0 + R[5]*x1 + R[8]*x2;
    float nrm = sqrtf(ox*ox + oy*oy + oz*oz + 1e-8f);
    float* c = cat + (size_t)(i0 + ip)*CATC;
    int m = h*8 + p;
    c[192 + m] = ox; c[288 + m] = oy; c[384 + m] = oz; c[480 + m] = nrm;
  }
}

// ---------------------------------------------------------------------------
// K6: out = cat @ Wout + bout. ROWS=3/block -> grid 256, x8-unrolled loads.
#define OROWS 3
__global__ void k_out(const float* __restrict__ cat, const float* __restrict__ Wout,
                      const float* __restrict__ bout, float* __restrict__ out) {
  __shared__ float cl[OROWS*CATC];
  int i0 = blockIdx.x*OROWS, t = threadIdx.x;
  for (int idx = t; idx < OROWS*CATC; idx += 384) cl[idx] = cat[(size_t)i0*CATC + idx];
  __syncthreads();
  float acc[OROWS];
  #pragma unroll
  for (int g = 0; g < OROWS; g++) acc[g] = 0.f;
  for (int r = 0; r < CATC; r += 8) {
    float wv[8];
    #pragma unroll
    for (int u = 0; u < 8; u++) wv[u] = Wout[(size_t)(r+u)*384 + t];
    #pragma unroll
    for (int u = 0; u < 8; u++) {
      #pragma unroll
      for (int g = 0; g < OROWS; g++) acc[g] += cl[g*CATC + r + u] * wv[u];
    }
  }
  float bo = bout[t];
  #pragma unroll
  for (int g = 0; g < OROWS; g++) out[(size_t)(i0+g)*384 + t] = acc[g] + bo;
}

// ---------------------------------------------------------------------------
extern "C" void kernel_launch(void* const* d_in, const int* in_sizes, int n_in,
                              void* d_out, int out_size, void* d_ws, size_t ws_size,
                              hipStream_t stream) {
  const float* s      = (const float*)d_in[0];
  const float* z      = (const float*)d_in[1];
  const float* rot    = (const float*)d_in[2];
  const float* trans  = (const float*)d_in[3];
  const float* Wq     = (const float*)d_in[4];
  const float* bq     = (const float*)d_in[5];
  const float* Wkv    = (const float*)d_in[6];
  const float* bkv    = (const float*)d_in[7];
  const float* Wqp    = (const float*)d_in[8];
  const float* bqp    = (const float*)d_in[9];
  const float* Wkvp   = (const float*)d_in[10];
  const float* bkvp   = (const float*)d_in[11];
  const float* Wb     = (const float*)d_in[12];
  const float* bb     = (const float*)d_in[13];
  const float* head_w = (const float*)d_in[14];
  const float* Wout   = (const float*)d_in[15];
  const float* bout   = (const float*)d_in[16];
  float* out = (float*)d_out;

  float* ws    = (float*)d_ws;
  float* q     = ws;                    // 147456
  float* kk    = q     + 147456;        // 147456
  float* vv    = kk    + 147456;        // 147456
  float* qpts  = vv    + 147456;        // 110592
  float* kvpts = qpts  + 110592;        // 331776
  unsigned short* p_bf = (unsigned short*)(kvpts + 331776); // 7077888 bf16 probs
  float* cat   = (float*)(p_bf + 7077888);                  // 1622016
  unsigned short* Bq = (unsigned short*)(cat + 1622016);    // 294912 bf16
  unsigned short* Vq = Bq + 294912;                         // 884736 bf16

  k_proj<<<768, 256, 0, stream>>>(s, rot, trans, Wq, bq, Wkv, bkv, Wqp, bqp,
                                  Wkvp, bkvp, q, kk, vv, qpts, kvpts);
  k_prep<<<48, 256, 0, stream>>>(kk, kvpts, Bq);
  k_prep_v<<<432, 256, 0, stream>>>(vv, kvpts, Vq);
  k_fused<<<768, 256, 0, stream>>>(q, qpts, z, Wb, bb, head_w, Bq, p_bf, cat);
  k_ov<<<dim3(48, 12), 256, 0, stream>>>(p_bf, Vq, rot, trans, cat);
  k_out<<<256, 384, 0, stream>>>(cat, Wout, bout, out);
}